// Round 14
// baseline (722.897 us; speedup 1.0000x reference)
//
#include <hip/hip_runtime.h>

#define N_N 100000
#define N_E 1600000
#define N_G 256
#define F_IN 28
#define HEADS 4
#define CH 64
#define NEG 0.2f
#define LN_EPS 1e-5f
#define NBKT 391   // ceil(N_N/256) coarse buckets (256 nodes each)
#define BCAP 6144  // per-bucket pair capacity (mean 4092, sigma 64 -> safe)

typedef __attribute__((ext_vector_type(8))) short short8v;   // 8 bf16
typedef __attribute__((ext_vector_type(4))) float float4v;   // MFMA acc

__device__ __forceinline__ float lrelu(float x) { return x > 0.f ? x : NEG * x; }

__device__ __forceinline__ float wsum(float v) {
#pragma unroll
  for (int o = 32; o > 0; o >>= 1) v += __shfl_xor(v, o, 64);
  return v;
}
__device__ __forceinline__ float wmax(float v) {
#pragma unroll
  for (int o = 32; o > 0; o >>= 1) v = fmaxf(v, __shfl_xor(v, o, 64));
  return v;
}

// bf16 helpers (storage-only compression in LDS)
__device__ __forceinline__ float bfs(unsigned short u) {
  return __uint_as_float((unsigned)u << 16);
}
__device__ __forceinline__ unsigned short f2bf(float v) {
  unsigned u = __float_as_uint(v);
  return (unsigned short)((u + 0x7fff + ((u >> 16) & 1)) >> 16);  // RNE
}

// ---------------- CSR build: two-level bucketed, coalesced ----------------
__global__ __launch_bounds__(256) void k_ccount(const int* __restrict__ dst, int* __restrict__ ccnt) {
  __shared__ int h[NBKT];
  int t = threadIdx.x;
  for (int i = t; i < NBKT; i += 256) h[i] = 0;
  __syncthreads();
  int base = blockIdx.x * 4096;
  int cnt = min(4096, N_E - base);
  for (int j = t; j < cnt; j += 256) atomicAdd(&h[dst[base + j] >> 8], 1);
  __syncthreads();
  for (int i = t; i < NBKT; i += 256)
    if (h[i]) atomicAdd(&ccnt[i], h[i]);
}

__global__ __launch_bounds__(512) void k_cscan(const int* __restrict__ ccnt, int* __restrict__ cbase,
                                               int* __restrict__ cfill) {
  __shared__ int l[512];
  int t = threadIdx.x;
  int v = (t < NBKT) ? ccnt[t] : 0;
  l[t] = v;
  __syncthreads();
  for (int o = 1; o < 512; o <<= 1) {
    int a = (t >= o) ? l[t - o] : 0;
    __syncthreads();
    l[t] += a;
    __syncthreads();
  }
  if (t < NBKT) {
    cbase[t] = l[t] - v;
    cfill[t] = l[t] - v;
  }
}

__global__ __launch_bounds__(256) void k_cscat(const int* __restrict__ src, const int* __restrict__ dst,
                                               int* cfill, unsigned long long* __restrict__ pairs) {
  __shared__ unsigned long long pl[4096];   // 32 KB
  __shared__ unsigned long long outp[4096]; // 32 KB
  __shared__ int h[NBKT], sc[NBKT], gpos[NBKT], f2[NBKT];
  int t = threadIdx.x;
  for (int i = t; i < NBKT; i += 256) {
    h[i] = 0;
    f2[i] = 0;
  }
  __syncthreads();
  int base = blockIdx.x * 4096;
  int cnt = min(4096, N_E - base);
  for (int j = t; j < cnt; j += 256) {
    int d = dst[base + j];
    pl[j] = ((unsigned long long)(unsigned)d << 32) | (unsigned)src[base + j];
    atomicAdd(&h[d >> 8], 1);
  }
  __syncthreads();
  for (int i = t; i < NBKT; i += 256) sc[i] = h[i];
  __syncthreads();
  for (int o = 1; o < NBKT; o <<= 1) {
    int v0 = 0, v1 = 0;
    int i2 = t + 256;
    if (t >= o) v0 = sc[t - o];
    if (i2 < NBKT && i2 >= o) v1 = sc[i2 - o];
    __syncthreads();
    if (t >= o) sc[t] += v0;
    if (i2 < NBKT && i2 >= o) sc[i2] += v1;
    __syncthreads();
  }
  for (int i = t; i < NBKT; i += 256)
    if (h[i]) gpos[i] = atomicAdd(&cfill[i], h[i]);
  __syncthreads();
  for (int j = t; j < cnt; j += 256) {
    unsigned long long p = pl[j];
    int bin = (int)(p >> 40);  // dst>>8
    int r = atomicAdd(&f2[bin], 1);
    outp[sc[bin] - h[bin] + r] = p;
  }
  __syncthreads();
  for (int j = t; j < cnt; j += 256) {
    unsigned long long p = outp[j];
    int bin = (int)(p >> 40);
    pairs[gpos[bin] + (j - (sc[bin] - h[bin]))] = p;
  }
}

__global__ __launch_bounds__(256) void k_build(const int* __restrict__ ccnt, const int* __restrict__ cbase,
                                               const unsigned long long* __restrict__ pairs,
                                               int* __restrict__ indptr, int* __restrict__ csr) {
  __shared__ unsigned long long pl[BCAP];  // 48 KB
  __shared__ int sl[BCAP];                 // 24 KB
  __shared__ int degl[256], lofs[256], fil[256];
  int nb = blockIdx.x, t = threadIdx.x;
  int gbase = cbase[nb], cnt = ccnt[nb];
  int nn = min(256, N_N - nb * 256);
  if (t == 0 && nb == 0) indptr[N_N] = N_E;
  if (cnt <= BCAP) {
    for (int j = t; j < cnt; j += 256) pl[j] = pairs[gbase + j];
    degl[t] = 0;
    __syncthreads();
    for (int j = t; j < cnt; j += 256) atomicAdd(&degl[(int)((pl[j] >> 32) & 255)], 1);
    __syncthreads();
    int v = degl[t];
    lofs[t] = v;
    __syncthreads();
    for (int o = 1; o < 256; o <<= 1) {
      int a = (t >= o) ? lofs[t - o] : 0;
      __syncthreads();
      lofs[t] += a;
      __syncthreads();
    }
    int excl = lofs[t] - v;  // exclusive prefix
    if (t < nn) indptr[nb * 256 + t] = gbase + excl;
    fil[t] = excl;
    __syncthreads();
    for (int j = t; j < cnt; j += 256) {
      unsigned long long p = pl[j];
      int node = (int)((p >> 32) & 255);
      int pos = atomicAdd(&fil[node], 1);
      sl[pos] = (int)(unsigned)p;
    }
    __syncthreads();
    int wv = t >> 6, lane = t & 63;
    for (int q = wv; q < 256; q += 4) {
      int d = degl[q];
      if (d <= 1) continue;
      int b = lofs[q] - d;
      if (d <= 64) {
        int vv = (lane < d) ? sl[b + lane] : 0x7fffffff;
        int rank = 0;
        for (int j2 = 0; j2 < d; ++j2) {
          int vj = __shfl(vv, j2, 64);
          rank += ((vj < vv) || (vj == vv && j2 < lane)) ? 1 : 0;
        }
        if (lane < d) sl[b + rank] = vv;
      } else if (lane == 0) {
        for (int j2 = b + 1; j2 < b + d; ++j2) {
          int key = sl[j2];
          int k2 = j2 - 1;
          while (k2 >= b && sl[k2] > key) { sl[k2 + 1] = sl[k2]; --k2; }
          sl[k2 + 1] = key;
        }
      }
    }
    __syncthreads();
    for (int j = t; j < cnt; j += 256) csr[gbase + j] = sl[j];
  } else if (t == 0) {
    for (int n = 0; n < nn; ++n) degl[n] = 0;
    for (int j = 0; j < cnt; ++j) degl[(int)((pairs[gbase + j] >> 32) & 255)]++;
    int run = 0;
    for (int n = 0; n < nn; ++n) {
      indptr[nb * 256 + n] = gbase + run;
      fil[n] = run;
      run += degl[n];
    }
    for (int j = 0; j < cnt; ++j) {
      unsigned long long p = pairs[gbase + j];
      int node = (int)((p >> 32) & 255);
      csr[gbase + fil[node]++] = (int)(unsigned)p;
    }
    for (int n = 0; n < nn; ++n) {
      int b = indptr[nb * 256 + n], e2 = b + degl[n];
      for (int j2 = b + 1; j2 < e2; ++j2) {
        int key = csr[j2];
        int k2 = j2 - 1;
        while (k2 >= b && csr[k2] > key) { csr[k2 + 1] = csr[k2]; --k2; }
        csr[k2 + 1] = key;
      }
    }
  }
}

// ---------------- graph ranges: batch is SORTED -> binary search ----------
__global__ __launch_bounds__(512) void k_gbounds(const int* __restrict__ batch, int* __restrict__ gptr) {
  int g = threadIdx.x;
  if (g > N_G) return;
  int lo = 0, hi = N_N;
  while (lo < hi) {
    int mid = (lo + hi) >> 1;
    if (batch[mid] < g) lo = mid + 1;
    else hi = mid;
  }
  gptr[g] = lo;
}

// ---------------- attention logits ----------------
template <int F>
__global__ __launch_bounds__(256) void k_avec(const float* __restrict__ W, const float* __restrict__ as_,
                                              const float* __restrict__ ad_, float* __restrict__ wsv,
                                              float* __restrict__ wdv) {
  int idx = blockIdx.x * 256 + threadIdx.x;
  if (idx >= HEADS * F) return;
  int h = idx / F, f = idx % F;
  float s = 0.f, d = 0.f;
  for (int c = 0; c < 64; ++c) {
    float w = W[(h * F + f) * 64 + c];
    s = fmaf(w, as_[h * 64 + c], s);
    d = fmaf(w, ad_[h * 64 + c], d);
  }
  wsv[idx] = s;
  wdv[idx] = d;
}

template <int F>
__global__ __launch_bounds__(256) void k_al2(const float* __restrict__ xin, const float* __restrict__ wsv,
                                             const float* __restrict__ wdv, float* __restrict__ al_s,
                                             float* __restrict__ al_d) {
  constexpr int FP = (F % 2 == 0) ? F + 1 : F;
  __shared__ float xl[64][FP];
  __shared__ float wsl[HEADS][F], wdl[HEADS][F];
  int t = threadIdx.x;
  for (int idx = t; idx < HEADS * F; idx += 256) {
    wsl[idx / F][idx % F] = wsv[idx];
    wdl[idx / F][idx % F] = wdv[idx];
  }
  int base = blockIdx.x * 64;
  for (int idx = t; idx < 64 * F; idx += 256) {
    int n = idx / F, f = idx % F;
    int i = base + n;
    xl[n][f] = (i < N_N) ? xin[(size_t)i * F + f] : 0.f;
  }
  __syncthreads();
  int n = t >> 2, h = t & 3;
  int i = base + n;
  if (i < N_N) {
    float s = 0.f, d = 0.f;
#pragma unroll
    for (int f = 0; f < F; ++f) {
      float xv = xl[n][f];
      s = fmaf(xv, wsl[h][f], s);
      d = fmaf(xv, wdl[h][f], d);
    }
    al_s[i * 4 + h] = s;
    al_d[i * 4 + h] = d;
  }
}

// ---------------- fused GAT layer (16 waves, 32 nodes/tile) ----------------
// 16 waves aggregate 2 nodes each (online weights, no max-subtraction: logits
// provably bounded), stage agg to LDS (bf16), 8 waves run the MFMA epilogue.
template <int F, int NW>
__global__ __launch_bounds__(64 * NW, 8) void k_gat(const float* __restrict__ xin, const int* __restrict__ indptr,
                                                    const int* __restrict__ csr, const float* __restrict__ al_s,
                                                    const float* __restrict__ al_d, const float* __restrict__ W,
                                                    const float* __restrict__ bias, float* __restrict__ xg) {
  constexpr int K = HEADS * F;        // 256 / 112
  constexpr int KP = (K + 31) & ~31;  // 256 / 128
  constexpr int KROW = KP + 8;
  __shared__ unsigned short Bt[64][KROW];   // W^T (bf16)
  __shared__ unsigned short Ash[32][KROW];  // agg (bf16), 32 nodes
  __shared__ int s_idx[NW][64];
  __shared__ float4 s_w[NW][64];
  int t = threadIdx.x;
  for (int idx = t; idx < K * 64; idx += 64 * NW) {
    int c = idx & 63, hf = idx >> 6;
    Bt[c][hf] = f2bf(W[(size_t)hf * 64 + c]);
  }
  if constexpr (KP > K) {
    for (int idx = t; idx < 64 * (KP - K); idx += 64 * NW)
      Bt[idx / (KP - K)][K + idx % (KP - K)] = 0;
    for (int idx = t; idx < 32 * (KP - K); idx += 64 * NW)
      Ash[idx / (KP - K)][K + idx % (KP - K)] = 0;
  }
  __syncthreads();
  int wv = t >> 6, lane = t & 63;
  int lanef = lane & 31;
  int half = lane >> 5;
  int l15 = lane & 15, g8 = (lane >> 4) * 8;
  float bias_c = bias[(wv & 3) * 16 + l15];
  for (int base = blockIdx.x * 32; base < N_N; base += gridDim.x * 32) {
#pragma unroll
    for (int rep = 0; rep < 2; ++rep) {
      int i = base + wv * 2 + rep;
      if (i < N_N) {
        int b = indptr[i], e = indptr[i + 1];
        float4 ad4 = *(const float4*)&al_d[i * 4];
        float4 as4 = *(const float4*)&al_s[i * 4];
        float ws0 = __expf(lrelu(as4.x + ad4.x));
        float ws1 = __expf(lrelu(as4.y + ad4.y));
        float ws2 = __expf(lrelu(as4.z + ad4.z));
        float ws3 = __expf(lrelu(as4.w + ad4.w));
        float xself = (lane < F) ? xin[(size_t)i * F + lane] : 0.f;
        float a0 = ws0 * xself, a1 = ws1 * xself, a2 = ws2 * xself, a3 = ws3 * xself;
        if (F == F_IN && half) { a0 = 0.f; a1 = 0.f; a2 = 0.f; a3 = 0.f; }
        float pd0 = 0.f, pd1 = 0.f, pd2 = 0.f, pd3 = 0.f;
        for (int cb = b; cb < e; cb += 64) {
          int cnt = min(64, e - cb);
          bool act = (cb + lane) < e;
          int s = 0;
          float w0 = 0.f, w1 = 0.f, w2 = 0.f, w3 = 0.f;
          if (act) {
            s = csr[cb + lane];
            float4 a4 = *(const float4*)&al_s[s * 4];
            w0 = __expf(lrelu(a4.x + ad4.x));
            w1 = __expf(lrelu(a4.y + ad4.y));
            w2 = __expf(lrelu(a4.z + ad4.z));
            w3 = __expf(lrelu(a4.w + ad4.w));
          }
          pd0 += w0; pd1 += w1; pd2 += w2; pd3 += w3;
          s_idx[wv][lane] = s;
          s_w[wv][lane] = make_float4(w0, w1, w2, w3);
          if (F == F_IN) {
            for (int je = 0; je < cnt; je += 16) {
              int sj[8];
#pragma unroll
              for (int u = 0; u < 8; ++u) sj[u] = s_idx[wv][je + 2 * u + half];
              float xr[8];
#pragma unroll
              for (int u = 0; u < 8; ++u)
                xr[u] = (lanef < F_IN) ? xin[(size_t)sj[u] * F_IN + lanef] : 0.f;
#pragma unroll
              for (int u = 0; u < 8; ++u) {
                float4 w4 = s_w[wv][je + 2 * u + half];
                a0 = fmaf(w4.x, xr[u], a0);
                a1 = fmaf(w4.y, xr[u], a1);
                a2 = fmaf(w4.z, xr[u], a2);
                a3 = fmaf(w4.w, xr[u], a3);
              }
            }
          } else {
            for (int je = 0; je < cnt; je += 8) {
              int sj[8];
#pragma unroll
              for (int u = 0; u < 8; ++u) sj[u] = s_idx[wv][je + u];
              float xr[8];
#pragma unroll
              for (int u = 0; u < 8; ++u) xr[u] = xin[(size_t)sj[u] * F + lane];
#pragma unroll
              for (int u = 0; u < 8; ++u) {
                float4 w4 = s_w[wv][je + u];
                a0 = fmaf(w4.x, xr[u], a0);
                a1 = fmaf(w4.y, xr[u], a1);
                a2 = fmaf(w4.z, xr[u], a2);
                a3 = fmaf(w4.w, xr[u], a3);
              }
            }
          }
        }
        if (F == F_IN) {
          a0 += __shfl_xor(a0, 32, 64);
          a1 += __shfl_xor(a1, 32, 64);
          a2 += __shfl_xor(a2, 32, 64);
          a3 += __shfl_xor(a3, 32, 64);
        }
        float dn0 = wsum(pd0) + ws0;
        float dn1 = wsum(pd1) + ws1;
        float dn2 = wsum(pd2) + ws2;
        float dn3 = wsum(pd3) + ws3;
        a0 /= dn0; a1 /= dn1; a2 /= dn2; a3 /= dn3;
        if (lane < F) {
          int n = wv * 2 + rep;
          Ash[n][0 * F + lane] = f2bf(a0);
          Ash[n][1 * F + lane] = f2bf(a1);
          Ash[n][2 * F + lane] = f2bf(a2);
          Ash[n][3 * F + lane] = f2bf(a3);
        }
      }
    }
    __syncthreads();
    if (wv < 8) {  // MFMA: wave = (rowTile 0..1) x (colTile 0..3)
      int rt = (wv >> 2) * 16, ct = (wv & 3) * 16;
      float4v c4 = {0.f, 0.f, 0.f, 0.f};
#pragma unroll
      for (int kk = 0; kk < KP; kk += 32) {
        short8v af = *(const short8v*)&Ash[rt + l15][kk + g8];
        short8v bf = *(const short8v*)&Bt[ct + l15][kk + g8];
        c4 = __builtin_amdgcn_mfma_f32_16x16x32_bf16(af, bf, c4, 0, 0, 0);
      }
#pragma unroll
      for (int reg = 0; reg < 4; ++reg) {
        int node = base + rt + (g8 >> 1) + reg;
        if (node < N_N) {
          float o = fmaxf(fmaf(c4[reg], 0.25f, bias_c), 0.f);
          xg[(size_t)node * 64 + ct + l15] = o;
        }
      }
    }
    __syncthreads();
  }
}

// ---- fused GIN (16 waves, 32 nodes/tile): agg + MFMA MLP + LN (+AL/+gate) --
template <int NW, bool FUSE_AL, bool FUSE_GATE>
__global__ __launch_bounds__(64 * NW, 8) void k_gin(const int* __restrict__ indptr, const int* __restrict__ csr,
                                                    const float* __restrict__ xg,
                                                    const float* __restrict__ w1,
                                                    const float* __restrict__ b1, const float* __restrict__ w2,
                                                    const float* __restrict__ b2, const float* __restrict__ lnw,
                                                    const float* __restrict__ lnb,
                                                    float* __restrict__ xo,
                                                    const float* __restrict__ wsv, const float* __restrict__ wdv,
                                                    float* __restrict__ al_s, float* __restrict__ al_d,
                                                    const float* __restrict__ gw1, const float* __restrict__ gb1,
                                                    const float* __restrict__ gw2, const float* __restrict__ gb2,
                                                    float* __restrict__ gate) {
  constexpr int KR = 72;
  __shared__ unsigned short W1t[64][KR], W2t[64][KR];
  __shared__ unsigned short GW1t[FUSE_GATE ? 64 : 1][FUSE_GATE ? KR : 1];
  __shared__ unsigned short WVt[FUSE_AL ? 16 : 1][FUSE_AL ? KR : 1];
  __shared__ unsigned short A1h[32][KR], A1l[32][KR], A2s[32][KR];
  __shared__ float A3[32][68];
  __shared__ unsigned short A4[FUSE_GATE ? 32 : 1][FUSE_GATE ? KR : 1];
  __shared__ float gred[4][32];
  int t = threadIdx.x;
  for (int idx = t; idx < 4096; idx += 64 * NW) {
    int k = idx >> 6, c = idx & 63;
    W1t[c][k] = f2bf(w1[idx]);
    W2t[c][k] = f2bf(w2[idx]);
    if constexpr (FUSE_GATE) GW1t[c][k] = f2bf(gw1[idx]);
  }
  if constexpr (FUSE_AL) {
    for (int idx = t; idx < 16 * 64; idx += 64 * NW) {
      int j = idx >> 6, k = idx & 63;
      float v = (j < 4) ? wsv[j * 64 + k] : (j < 8 ? wdv[(j - 4) * 64 + k] : 0.f);
      WVt[j][k] = f2bf(v);
    }
  }
  __syncthreads();
  int wv = t >> 6, lane = t & 63;
  int l15 = lane & 15, g8 = (lane >> 4) * 8;
  int ct = (wv & 3) * 16, rt = ((wv >> 2) & 1) * 16;  // tile coords (wv<8)
  float b1c = b1[ct + l15], b2c = b2[ct + l15];
  float gb1c = 0.f, gw2c = 0.f;
  if constexpr (FUSE_GATE) {
    gb1c = gb1[ct + l15];
    gw2c = gw2[ct + l15];
  }
  float lnwv = lnw[lane], lnbv = lnb[lane];
  float gb2v = FUSE_GATE ? gb2[0] : 0.f;
  for (int base = blockIdx.x * 32; base < N_N; base += gridDim.x * 32) {
    float xis[2];
#pragma unroll
    for (int rep = 0; rep < 2; ++rep) {
      int i = base + wv * 2 + rep;
      if (i < N_N) {
        int b = indptr[i], e = indptr[i + 1];
        float xi = xg[(size_t)i * 64 + lane];
        xis[rep] = xi;
        float acc = xi;
        for (int j = b; j < e; j += 8) {
          int cj[8];
#pragma unroll
          for (int u = 0; u < 8; ++u) cj[u] = csr[min(j + u, e - 1)];
          float v[8];
#pragma unroll
          for (int u = 0; u < 8; ++u) v[u] = xg[(size_t)cj[u] * 64 + lane];
#pragma unroll
          for (int u = 0; u < 8; ++u) acc += (j + u) < e ? v[u] : 0.f;
        }
        int n = wv * 2 + rep;
        unsigned short hb = f2bf(acc);
        A1h[n][lane] = hb;
        A1l[n][lane] = f2bf(acc - bfs(hb));
      }
    }
    __syncthreads();
    if (wv < 8) {  // MLP1: relu(A1 @ W1 + b1) -> A2 (bf16)
      float4v c4 = {0.f, 0.f, 0.f, 0.f};
#pragma unroll
      for (int kk = 0; kk < 64; kk += 32) {
        short8v bf = *(const short8v*)&W1t[ct + l15][kk + g8];
        short8v ah = *(const short8v*)&A1h[rt + l15][kk + g8];
        c4 = __builtin_amdgcn_mfma_f32_16x16x32_bf16(ah, bf, c4, 0, 0, 0);
        short8v al = *(const short8v*)&A1l[rt + l15][kk + g8];
        c4 = __builtin_amdgcn_mfma_f32_16x16x32_bf16(al, bf, c4, 0, 0, 0);
      }
#pragma unroll
      for (int reg = 0; reg < 4; ++reg)
        A2s[rt + (g8 >> 1) + reg][ct + l15] = f2bf(fmaxf(c4[reg] + b1c, 0.f));
    }
    __syncthreads();
    if (wv < 8) {  // MLP2: A2 @ W2 + b2 -> A3 (f32)
      float4v c4 = {0.f, 0.f, 0.f, 0.f};
#pragma unroll
      for (int kk = 0; kk < 64; kk += 32) {
        short8v af = *(const short8v*)&A2s[rt + l15][kk + g8];
        short8v bf = *(const short8v*)&W2t[ct + l15][kk + g8];
        c4 = __builtin_amdgcn_mfma_f32_16x16x32_bf16(af, bf, c4, 0, 0, 0);
      }
#pragma unroll
      for (int reg = 0; reg < 4; ++reg) A3[rt + (g8 >> 1) + reg][ct + l15] = c4[reg] + b2c;
    }
    __syncthreads();
#pragma unroll
    for (int rep = 0; rep < 2; ++rep) {
      int i = base + wv * 2 + rep;
      if (i < N_N) {
        int n = wv * 2 + rep;
        float res = xis[rep] + A3[n][lane];
        float mu = wsum(res) * (1.f / 64.f);
        float d = res - mu;
        float var = wsum(d * d) * (1.f / 64.f);
        float xov = fmaf(d * rsqrtf(var + LN_EPS), lnwv, lnbv);
        xo[(size_t)i * 64 + lane] = xov;
        if constexpr (FUSE_AL) {
          unsigned short hb = f2bf(xov);
          A1h[n][lane] = hb;
          A1l[n][lane] = f2bf(xov - bfs(hb));
        }
        if constexpr (FUSE_GATE) A4[n][lane] = f2bf(xov);
      }
    }
    if constexpr (FUSE_AL) {
      __syncthreads();
      if (wv < 2) {  // [32 nodes x 64] @ [64 x 16 logit cols]; rows wv*16
        float4v c4 = {0.f, 0.f, 0.f, 0.f};
#pragma unroll
        for (int kk = 0; kk < 64; kk += 32) {
          short8v bf = *(const short8v*)&WVt[l15][kk + g8];
          short8v ah = *(const short8v*)&A1h[wv * 16 + l15][kk + g8];
          c4 = __builtin_amdgcn_mfma_f32_16x16x32_bf16(ah, bf, c4, 0, 0, 0);
          short8v al = *(const short8v*)&A1l[wv * 16 + l15][kk + g8];
          c4 = __builtin_amdgcn_mfma_f32_16x16x32_bf16(al, bf, c4, 0, 0, 0);
        }
#pragma unroll
        for (int reg = 0; reg < 4; ++reg) {
          int node = base + wv * 16 + (g8 >> 1) + reg;
          if (node < N_N) {
            if (l15 < 4) al_s[node * 4 + l15] = c4[reg];
            else if (l15 < 8) al_d[node * 4 + (l15 - 4)] = c4[reg];
          }
        }
      }
      __syncthreads();
    }
    if constexpr (FUSE_GATE) {
      __syncthreads();
      if (wv < 8) {  // gate hidden tile: relu(A4 @ GW1 + gb1) . gw2 (partial)
        float4v c4 = {0.f, 0.f, 0.f, 0.f};
#pragma unroll
        for (int kk = 0; kk < 64; kk += 32) {
          short8v af = *(const short8v*)&A4[rt + l15][kk + g8];
          short8v bf = *(const short8v*)&GW1t[ct + l15][kk + g8];
          c4 = __builtin_amdgcn_mfma_f32_16x16x32_bf16(af, bf, c4, 0, 0, 0);
        }
#pragma unroll
        for (int reg = 0; reg < 4; ++reg) {
          float m = fmaxf(c4[reg] + gb1c, 0.f) * gw2c;
          m += __shfl_xor(m, 1, 64);
          m += __shfl_xor(m, 2, 64);
          m += __shfl_xor(m, 4, 64);
          m += __shfl_xor(m, 8, 64);
          if (l15 == 0) gred[wv & 3][rt + (g8 >> 1) + reg] = m;
        }
      }
      __syncthreads();
      if (wv == 0 && lane < 32) {
        int node = base + lane;
        if (node < N_N)
          gate[node] = gred[0][lane] + gred[1][lane] + gred[2][lane] + gred[3][lane] + gb2v;
      }
      __syncthreads();
    }
  }
}

// ---------------- global attention pool ----------------
__global__ __launch_bounds__(256) void k_pool(const int* __restrict__ gptr, const float* __restrict__ gate,
                                              const float* __restrict__ x2, float* __restrict__ pooled) {
  int g = blockIdx.x;
  int t = threadIdx.x, wv = t >> 6, lane = t & 63;
  __shared__ float red[256];
  int b = gptr[g], e = gptr[g + 1];
  if (b == e) {
    if (t < 64) pooled[g * 64 + t] = 0.f;
    return;
  }
  float m = -1e30f;
  for (int j = b + t; j < e; j += 256) m = fmaxf(m, gate[j]);
  m = wmax(m);
  if (lane == 0) red[wv] = m;
  __syncthreads();
  m = fmaxf(fmaxf(red[0], red[1]), fmaxf(red[2], red[3]));
  __syncthreads();
  float dn = 0.f;
  for (int j = b + t; j < e; j += 256) dn += __expf(gate[j] - m);
  dn = wsum(dn);
  if (lane == 0) red[wv] = dn;
  __syncthreads();
  dn = red[0] + red[1] + red[2] + red[3];
  __syncthreads();
  float acc = 0.f;
  for (int j = b + wv; j < e; j += 4) acc = fmaf(__expf(gate[j] - m), x2[(size_t)j * 64 + lane], acc);
  red[t] = acc;
  __syncthreads();
  if (t < 64) pooled[g * 64 + t] = (red[t] + red[t + 64] + red[t + 128] + red[t + 192]) / dn;
}

// ---------------- head MLP ----------------
__global__ __launch_bounds__(128) void k_head(const float* __restrict__ pooled, const float* __restrict__ l1w,
                                              const float* __restrict__ l1b, const float* __restrict__ lnfw,
                                              const float* __restrict__ lnfb, const float* __restrict__ l2w,
                                              const float* __restrict__ l2b, float* __restrict__ out) {
  int g = blockIdx.x, t = threadIdx.x;
  __shared__ float pl[64], zl[128], red[2];
  if (t < 64) pl[t] = pooled[g * 64 + t];
  __syncthreads();
  float y = l1b[t];
#pragma unroll 8
  for (int k = 0; k < 64; ++k) y = fmaf(pl[k], l1w[k * 128 + t], y);
  int wv = t >> 6, lane = t & 63;
  float s = wsum(y);
  if (lane == 0) red[wv] = s;
  __syncthreads();
  float mu = (red[0] + red[1]) * (1.f / 128.f);
  float d = y - mu;
  __syncthreads();
  s = wsum(d * d);
  if (lane == 0) red[wv] = s;
  __syncthreads();
  float var = (red[0] + red[1]) * (1.f / 128.f);
  float z = fmaxf(fmaf(d * rsqrtf(var + LN_EPS), lnfw[t], lnfb[t]), 0.f);
  zl[t] = z;
  __syncthreads();
  if (t < 6) {
    float o = l2b[t];
    for (int k = 0; k < 128; ++k) o = fmaf(zl[k], l2w[k * 6 + t], o);
    out[g * 6 + t] = o;
  }
}

extern "C" void kernel_launch(void* const* d_in, const int* in_sizes, int n_in,
                              void* d_out, int out_size, void* d_ws, size_t ws_size,
                              hipStream_t stream) {
  const float* x = (const float*)d_in[0];
  const int* src = (const int*)d_in[1];
  const int* dst = (const int*)d_in[2];
  const int* batch = (const int*)d_in[3];
  const float* W1 = (const float*)d_in[4];
  const float* a1s = (const float*)d_in[5];
  const float* a1d = (const float*)d_in[6];
  const float* bg1 = (const float*)d_in[7];
  const float* m1w1 = (const float*)d_in[8];
  const float* m1b1 = (const float*)d_in[9];
  const float* m1w2 = (const float*)d_in[10];
  const float* m1b2 = (const float*)d_in[11];
  const float* ln1w = (const float*)d_in[12];
  const float* ln1b = (const float*)d_in[13];
  const float* W2 = (const float*)d_in[14];
  const float* a2s = (const float*)d_in[15];
  const float* a2d = (const float*)d_in[16];
  const float* bg2 = (const float*)d_in[17];
  const float* m2w1 = (const float*)d_in[18];
  const float* m2b1 = (const float*)d_in[19];
  const float* m2w2 = (const float*)d_in[20];
  const float* m2b2 = (const float*)d_in[21];
  const float* ln2w = (const float*)d_in[22];
  const float* ln2b = (const float*)d_in[23];
  const float* gw1 = (const float*)d_in[24];
  const float* gb1 = (const float*)d_in[25];
  const float* gw2 = (const float*)d_in[26];
  const float* gb2 = (const float*)d_in[27];
  const float* l1w = (const float*)d_in[28];
  const float* l1b = (const float*)d_in[29];
  const float* lnfw = (const float*)d_in[30];
  const float* lnfb = (const float*)d_in[31];
  const float* l2w = (const float*)d_in[32];
  const float* l2b = (const float*)d_in[33];
  float* out = (float*)d_out;

  char* ws = (char*)d_ws;
  size_t off = 0;
  auto alloc = [&](size_t bytes) -> void* {
    void* p = ws + off;
    off += (bytes + 255) & ~(size_t)255;
    return p;
  };
  int* indptr = (int*)alloc((N_N + 1) * sizeof(int));
  int* csr = (int*)alloc((size_t)N_E * sizeof(int));
  unsigned long long* pairs = (unsigned long long*)alloc((size_t)N_E * sizeof(unsigned long long));
  int* ccnt = (int*)alloc(NBKT * sizeof(int));
  int* cbase = (int*)alloc(NBKT * sizeof(int));
  int* cfill = (int*)alloc(NBKT * sizeof(int));
  int* gptr = (int*)alloc(257 * sizeof(int));
  float* wsv = (float*)alloc(HEADS * 64 * sizeof(float));
  float* wdv = (float*)alloc(HEADS * 64 * sizeof(float));
  float* al_s = (float*)alloc((size_t)N_N * 4 * sizeof(float));
  float* al_d = (float*)alloc((size_t)N_N * 4 * sizeof(float));
  float* gate = (float*)alloc((size_t)N_N * sizeof(float));
  float* pooled = (float*)alloc(N_G * 64 * sizeof(float));
  float* xg = (float*)alloc((size_t)N_N * 64 * sizeof(float));
  float* xv = (float*)alloc((size_t)N_N * 64 * sizeof(float));
  (void)ws_size; (void)n_in; (void)in_sizes; (void)out_size;

  const int NCB = (N_E + 4095) / 4096;  // 391

  hipMemsetAsync(ccnt, 0, NBKT * sizeof(int), stream);
  k_ccount<<<NCB, 256, 0, stream>>>(dst, ccnt);
  k_cscan<<<1, 512, 0, stream>>>(ccnt, cbase, cfill);
  k_cscat<<<NCB, 256, 0, stream>>>(src, dst, cfill, pairs);
  k_build<<<NBKT, 256, 0, stream>>>(ccnt, cbase, pairs, indptr, csr);
  k_gbounds<<<1, 512, 0, stream>>>(batch, gptr);

  // ---- layer 1 ----
  k_avec<F_IN><<<1, 256, 0, stream>>>(W1, a1s, a1d, wsv, wdv);
  k_al2<F_IN><<<(N_N + 63) / 64, 256, 0, stream>>>(x, wsv, wdv, al_s, al_d);
  k_gat<F_IN, 16><<<1024, 1024, 0, stream>>>(x, indptr, csr, al_s, al_d, W1, bg1, xg);
  k_avec<CH><<<1, 256, 0, stream>>>(W2, a2s, a2d, wsv, wdv);  // layer-2 logit vectors
  k_gin<16, true, false><<<1024, 1024, 0, stream>>>(indptr, csr, xg, m1w1, m1b1, m1w2, m1b2, ln1w, ln1b,
                                                    xv, wsv, wdv, al_s, al_d, gw1, gb1, gw2, gb2, gate);
  // ---- layer 2 ----
  k_gat<CH, 16><<<1024, 1024, 0, stream>>>(xv, indptr, csr, al_s, al_d, W2, bg2, xg);
  k_gin<16, false, true><<<1024, 1024, 0, stream>>>(indptr, csr, xg, m2w1, m2b1, m2w2, m2b2, ln2w, ln2b,
                                                    xv, wsv, wdv, al_s, al_d, gw1, gb1, gw2, gb2, gate);
  // ---- pooling + head ----
  k_pool<<<N_G, 256, 0, stream>>>(gptr, gate, xv, pooled);
  k_head<<<N_G, 128, 0, stream>>>(pooled, l1w, l1b, lnfw, lnfb, l2w, l2b, out);
}

// Round 15
// 680.149 us; speedup vs baseline: 1.0629x; 1.0629x over previous
//
#include <hip/hip_runtime.h>

#define N_N 100000
#define N_E 1600000
#define N_G 256
#define F_IN 28
#define HEADS 4
#define CH 64
#define NEG 0.2f
#define LN_EPS 1e-5f
#define NBKT 391   // ceil(N_N/256) coarse buckets (256 nodes each)
#define BCAP 6144  // per-bucket pair capacity (mean 4092, sigma 64 -> safe)

typedef __attribute__((ext_vector_type(8))) short short8v;   // 8 bf16
typedef __attribute__((ext_vector_type(4))) float float4v;   // MFMA acc

__device__ __forceinline__ float lrelu(float x) { return x > 0.f ? x : NEG * x; }

__device__ __forceinline__ float wsum(float v) {
#pragma unroll
  for (int o = 32; o > 0; o >>= 1) v += __shfl_xor(v, o, 64);
  return v;
}
__device__ __forceinline__ float wmax(float v) {
#pragma unroll
  for (int o = 32; o > 0; o >>= 1) v = fmaxf(v, __shfl_xor(v, o, 64));
  return v;
}

// bf16 helpers (storage-only compression in LDS)
__device__ __forceinline__ float bfs(unsigned short u) {
  return __uint_as_float((unsigned)u << 16);
}
__device__ __forceinline__ unsigned short f2bf(float v) {
  unsigned u = __float_as_uint(v);
  return (unsigned short)((u + 0x7fff + ((u >> 16) & 1)) >> 16);  // RNE
}

// ---------------- CSR build: two-level bucketed, coalesced ----------------
__global__ __launch_bounds__(256) void k_ccount(const int* __restrict__ dst, int* __restrict__ ccnt) {
  __shared__ int h[NBKT];
  int t = threadIdx.x;
  for (int i = t; i < NBKT; i += 256) h[i] = 0;
  __syncthreads();
  int base = blockIdx.x * 4096;
  int cnt = min(4096, N_E - base);
  for (int j = t; j < cnt; j += 256) atomicAdd(&h[dst[base + j] >> 8], 1);
  __syncthreads();
  for (int i = t; i < NBKT; i += 256)
    if (h[i]) atomicAdd(&ccnt[i], h[i]);
}

__global__ __launch_bounds__(512) void k_cscan(const int* __restrict__ ccnt, int* __restrict__ cbase,
                                               int* __restrict__ cfill) {
  __shared__ int l[512];
  int t = threadIdx.x;
  int v = (t < NBKT) ? ccnt[t] : 0;
  l[t] = v;
  __syncthreads();
  for (int o = 1; o < 512; o <<= 1) {
    int a = (t >= o) ? l[t - o] : 0;
    __syncthreads();
    l[t] += a;
    __syncthreads();
  }
  if (t < NBKT) {
    cbase[t] = l[t] - v;
    cfill[t] = l[t] - v;
  }
}

__global__ __launch_bounds__(256) void k_cscat(const int* __restrict__ src, const int* __restrict__ dst,
                                               int* cfill, unsigned long long* __restrict__ pairs) {
  __shared__ unsigned long long pl[4096];   // 32 KB
  __shared__ unsigned long long outp[4096]; // 32 KB
  __shared__ int h[NBKT], sc[NBKT], gpos[NBKT], f2[NBKT];
  int t = threadIdx.x;
  for (int i = t; i < NBKT; i += 256) {
    h[i] = 0;
    f2[i] = 0;
  }
  __syncthreads();
  int base = blockIdx.x * 4096;
  int cnt = min(4096, N_E - base);
  for (int j = t; j < cnt; j += 256) {
    int d = dst[base + j];
    pl[j] = ((unsigned long long)(unsigned)d << 32) | (unsigned)src[base + j];
    atomicAdd(&h[d >> 8], 1);
  }
  __syncthreads();
  for (int i = t; i < NBKT; i += 256) sc[i] = h[i];
  __syncthreads();
  for (int o = 1; o < NBKT; o <<= 1) {
    int v0 = 0, v1 = 0;
    int i2 = t + 256;
    if (t >= o) v0 = sc[t - o];
    if (i2 < NBKT && i2 >= o) v1 = sc[i2 - o];
    __syncthreads();
    if (t >= o) sc[t] += v0;
    if (i2 < NBKT && i2 >= o) sc[i2] += v1;
    __syncthreads();
  }
  for (int i = t; i < NBKT; i += 256)
    if (h[i]) gpos[i] = atomicAdd(&cfill[i], h[i]);
  __syncthreads();
  for (int j = t; j < cnt; j += 256) {
    unsigned long long p = pl[j];
    int bin = (int)(p >> 40);  // dst>>8
    int r = atomicAdd(&f2[bin], 1);
    outp[sc[bin] - h[bin] + r] = p;
  }
  __syncthreads();
  for (int j = t; j < cnt; j += 256) {
    unsigned long long p = outp[j];
    int bin = (int)(p >> 40);
    pairs[gpos[bin] + (j - (sc[bin] - h[bin]))] = p;
  }
}

__global__ __launch_bounds__(256) void k_build(const int* __restrict__ ccnt, const int* __restrict__ cbase,
                                               const unsigned long long* __restrict__ pairs,
                                               int* __restrict__ indptr, int* __restrict__ csr) {
  __shared__ unsigned long long pl[BCAP];  // 48 KB
  __shared__ int sl[BCAP];                 // 24 KB
  __shared__ int degl[256], lofs[256], fil[256];
  int nb = blockIdx.x, t = threadIdx.x;
  int gbase = cbase[nb], cnt = ccnt[nb];
  int nn = min(256, N_N - nb * 256);
  if (t == 0 && nb == 0) indptr[N_N] = N_E;
  if (cnt <= BCAP) {
    for (int j = t; j < cnt; j += 256) pl[j] = pairs[gbase + j];
    degl[t] = 0;
    __syncthreads();
    for (int j = t; j < cnt; j += 256) atomicAdd(&degl[(int)((pl[j] >> 32) & 255)], 1);
    __syncthreads();
    int v = degl[t];
    lofs[t] = v;
    __syncthreads();
    for (int o = 1; o < 256; o <<= 1) {
      int a = (t >= o) ? lofs[t - o] : 0;
      __syncthreads();
      lofs[t] += a;
      __syncthreads();
    }
    int excl = lofs[t] - v;  // exclusive prefix
    if (t < nn) indptr[nb * 256 + t] = gbase + excl;
    fil[t] = excl;
    __syncthreads();
    for (int j = t; j < cnt; j += 256) {
      unsigned long long p = pl[j];
      int node = (int)((p >> 32) & 255);
      int pos = atomicAdd(&fil[node], 1);
      sl[pos] = (int)(unsigned)p;
    }
    __syncthreads();
    int wv = t >> 6, lane = t & 63;
    for (int q = wv; q < 256; q += 4) {
      int d = degl[q];
      if (d <= 1) continue;
      int b = lofs[q] - d;
      if (d <= 64) {
        int vv = (lane < d) ? sl[b + lane] : 0x7fffffff;
        int rank = 0;
        for (int j2 = 0; j2 < d; ++j2) {
          int vj = __shfl(vv, j2, 64);
          rank += ((vj < vv) || (vj == vv && j2 < lane)) ? 1 : 0;
        }
        if (lane < d) sl[b + rank] = vv;
      } else if (lane == 0) {
        for (int j2 = b + 1; j2 < b + d; ++j2) {
          int key = sl[j2];
          int k2 = j2 - 1;
          while (k2 >= b && sl[k2] > key) { sl[k2 + 1] = sl[k2]; --k2; }
          sl[k2 + 1] = key;
        }
      }
    }
    __syncthreads();
    for (int j = t; j < cnt; j += 256) csr[gbase + j] = sl[j];
  } else if (t == 0) {
    for (int n = 0; n < nn; ++n) degl[n] = 0;
    for (int j = 0; j < cnt; ++j) degl[(int)((pairs[gbase + j] >> 32) & 255)]++;
    int run = 0;
    for (int n = 0; n < nn; ++n) {
      indptr[nb * 256 + n] = gbase + run;
      fil[n] = run;
      run += degl[n];
    }
    for (int j = 0; j < cnt; ++j) {
      unsigned long long p = pairs[gbase + j];
      int node = (int)((p >> 32) & 255);
      csr[gbase + fil[node]++] = (int)(unsigned)p;
    }
    for (int n = 0; n < nn; ++n) {
      int b = indptr[nb * 256 + n], e2 = b + degl[n];
      for (int j2 = b + 1; j2 < e2; ++j2) {
        int key = csr[j2];
        int k2 = j2 - 1;
        while (k2 >= b && csr[k2] > key) { csr[k2 + 1] = csr[k2]; --k2; }
        csr[k2 + 1] = key;
      }
    }
  }
}

// ---------------- graph ranges: batch is SORTED -> binary search ----------
__global__ __launch_bounds__(512) void k_gbounds(const int* __restrict__ batch, int* __restrict__ gptr) {
  int g = threadIdx.x;
  if (g > N_G) return;
  int lo = 0, hi = N_N;
  while (lo < hi) {
    int mid = (lo + hi) >> 1;
    if (batch[mid] < g) lo = mid + 1;
    else hi = mid;
  }
  gptr[g] = lo;
}

// ---------------- attention logits ----------------
template <int F>
__global__ __launch_bounds__(256) void k_avec(const float* __restrict__ W, const float* __restrict__ as_,
                                              const float* __restrict__ ad_, float* __restrict__ wsv,
                                              float* __restrict__ wdv) {
  int idx = blockIdx.x * 256 + threadIdx.x;
  if (idx >= HEADS * F) return;
  int h = idx / F, f = idx % F;
  float s = 0.f, d = 0.f;
  for (int c = 0; c < 64; ++c) {
    float w = W[(h * F + f) * 64 + c];
    s = fmaf(w, as_[h * 64 + c], s);
    d = fmaf(w, ad_[h * 64 + c], d);
  }
  wsv[idx] = s;
  wdv[idx] = d;
}

template <int F>
__global__ __launch_bounds__(256) void k_al2(const float* __restrict__ xin, const float* __restrict__ wsv,
                                             const float* __restrict__ wdv, float* __restrict__ al_s,
                                             float* __restrict__ al_d) {
  constexpr int FP = (F % 2 == 0) ? F + 1 : F;
  __shared__ float xl[64][FP];
  __shared__ float wsl[HEADS][F], wdl[HEADS][F];
  int t = threadIdx.x;
  for (int idx = t; idx < HEADS * F; idx += 256) {
    wsl[idx / F][idx % F] = wsv[idx];
    wdl[idx / F][idx % F] = wdv[idx];
  }
  int base = blockIdx.x * 64;
  for (int idx = t; idx < 64 * F; idx += 256) {
    int n = idx / F, f = idx % F;
    int i = base + n;
    xl[n][f] = (i < N_N) ? xin[(size_t)i * F + f] : 0.f;
  }
  __syncthreads();
  int n = t >> 2, h = t & 3;
  int i = base + n;
  if (i < N_N) {
    float s = 0.f, d = 0.f;
#pragma unroll
    for (int f = 0; f < F; ++f) {
      float xv = xl[n][f];
      s = fmaf(xv, wsl[h][f], s);
      d = fmaf(xv, wdl[h][f], d);
    }
    al_s[i * 4 + h] = s;
    al_d[i * 4 + h] = d;
  }
}

// ---------------- fused GAT layer (16 waves, 32 nodes/tile) ----------------
// 16 waves aggregate 2 nodes each (online weights, no max-subtraction: logits
// provably bounded), stage agg to LDS (bf16), 8 waves run the MFMA epilogue.
template <int F, int NW>
__global__ __launch_bounds__(64 * NW, 4) void k_gat(const float* __restrict__ xin, const int* __restrict__ indptr,
                                                    const int* __restrict__ csr, const float* __restrict__ al_s,
                                                    const float* __restrict__ al_d, const float* __restrict__ W,
                                                    const float* __restrict__ bias, float* __restrict__ xg) {
  constexpr int K = HEADS * F;        // 256 / 112
  constexpr int KP = (K + 31) & ~31;  // 256 / 128
  constexpr int KROW = KP + 8;
  __shared__ unsigned short Bt[64][KROW];   // W^T (bf16)
  __shared__ unsigned short Ash[32][KROW];  // agg (bf16), 32 nodes
  __shared__ int s_idx[NW][64];
  __shared__ float4 s_w[NW][64];
  int t = threadIdx.x;
  for (int idx = t; idx < K * 64; idx += 64 * NW) {
    int c = idx & 63, hf = idx >> 6;
    Bt[c][hf] = f2bf(W[(size_t)hf * 64 + c]);
  }
  if constexpr (KP > K) {
    for (int idx = t; idx < 64 * (KP - K); idx += 64 * NW)
      Bt[idx / (KP - K)][K + idx % (KP - K)] = 0;
    for (int idx = t; idx < 32 * (KP - K); idx += 64 * NW)
      Ash[idx / (KP - K)][K + idx % (KP - K)] = 0;
  }
  __syncthreads();
  int wv = t >> 6, lane = t & 63;
  int lanef = lane & 31;
  int half = lane >> 5;
  int l15 = lane & 15, g8 = (lane >> 4) * 8;
  float bias_c = bias[(wv & 3) * 16 + l15];
  for (int base = blockIdx.x * 32; base < N_N; base += gridDim.x * 32) {
#pragma unroll
    for (int rep = 0; rep < 2; ++rep) {
      int i = base + wv * 2 + rep;
      if (i < N_N) {
        int b = indptr[i], e = indptr[i + 1];
        float4 ad4 = *(const float4*)&al_d[i * 4];
        float4 as4 = *(const float4*)&al_s[i * 4];
        float ws0 = __expf(lrelu(as4.x + ad4.x));
        float ws1 = __expf(lrelu(as4.y + ad4.y));
        float ws2 = __expf(lrelu(as4.z + ad4.z));
        float ws3 = __expf(lrelu(as4.w + ad4.w));
        float xself = (lane < F) ? xin[(size_t)i * F + lane] : 0.f;
        float a0 = ws0 * xself, a1 = ws1 * xself, a2 = ws2 * xself, a3 = ws3 * xself;
        if (F == F_IN && half) { a0 = 0.f; a1 = 0.f; a2 = 0.f; a3 = 0.f; }
        float pd0 = 0.f, pd1 = 0.f, pd2 = 0.f, pd3 = 0.f;
        for (int cb = b; cb < e; cb += 64) {
          int cnt = min(64, e - cb);
          bool act = (cb + lane) < e;
          int s = 0;
          float w0 = 0.f, w1 = 0.f, w2 = 0.f, w3 = 0.f;
          if (act) {
            s = csr[cb + lane];
            float4 a4 = *(const float4*)&al_s[s * 4];
            w0 = __expf(lrelu(a4.x + ad4.x));
            w1 = __expf(lrelu(a4.y + ad4.y));
            w2 = __expf(lrelu(a4.z + ad4.z));
            w3 = __expf(lrelu(a4.w + ad4.w));
          }
          pd0 += w0; pd1 += w1; pd2 += w2; pd3 += w3;
          s_idx[wv][lane] = s;
          s_w[wv][lane] = make_float4(w0, w1, w2, w3);
          if (F == F_IN) {
            for (int je = 0; je < cnt; je += 16) {
              int sj[8];
#pragma unroll
              for (int u = 0; u < 8; ++u) sj[u] = s_idx[wv][je + 2 * u + half];
              float xr[8];
#pragma unroll
              for (int u = 0; u < 8; ++u)
                xr[u] = (lanef < F_IN) ? xin[(size_t)sj[u] * F_IN + lanef] : 0.f;
#pragma unroll
              for (int u = 0; u < 8; ++u) {
                float4 w4 = s_w[wv][je + 2 * u + half];
                a0 = fmaf(w4.x, xr[u], a0);
                a1 = fmaf(w4.y, xr[u], a1);
                a2 = fmaf(w4.z, xr[u], a2);
                a3 = fmaf(w4.w, xr[u], a3);
              }
            }
          } else {
            for (int je = 0; je < cnt; je += 8) {
              int sj[8];
#pragma unroll
              for (int u = 0; u < 8; ++u) sj[u] = s_idx[wv][je + u];
              float xr[8];
#pragma unroll
              for (int u = 0; u < 8; ++u) xr[u] = xin[(size_t)sj[u] * F + lane];
#pragma unroll
              for (int u = 0; u < 8; ++u) {
                float4 w4 = s_w[wv][je + u];
                a0 = fmaf(w4.x, xr[u], a0);
                a1 = fmaf(w4.y, xr[u], a1);
                a2 = fmaf(w4.z, xr[u], a2);
                a3 = fmaf(w4.w, xr[u], a3);
              }
            }
          }
        }
        if (F == F_IN) {
          a0 += __shfl_xor(a0, 32, 64);
          a1 += __shfl_xor(a1, 32, 64);
          a2 += __shfl_xor(a2, 32, 64);
          a3 += __shfl_xor(a3, 32, 64);
        }
        float dn0 = wsum(pd0) + ws0;
        float dn1 = wsum(pd1) + ws1;
        float dn2 = wsum(pd2) + ws2;
        float dn3 = wsum(pd3) + ws3;
        a0 /= dn0; a1 /= dn1; a2 /= dn2; a3 /= dn3;
        if (lane < F) {
          int n = wv * 2 + rep;
          Ash[n][0 * F + lane] = f2bf(a0);
          Ash[n][1 * F + lane] = f2bf(a1);
          Ash[n][2 * F + lane] = f2bf(a2);
          Ash[n][3 * F + lane] = f2bf(a3);
        }
      }
    }
    __syncthreads();
    if (wv < 8) {  // MFMA: wave = (rowTile 0..1) x (colTile 0..3)
      int rt = (wv >> 2) * 16, ct = (wv & 3) * 16;
      float4v c4 = {0.f, 0.f, 0.f, 0.f};
#pragma unroll
      for (int kk = 0; kk < KP; kk += 32) {
        short8v af = *(const short8v*)&Ash[rt + l15][kk + g8];
        short8v bf = *(const short8v*)&Bt[ct + l15][kk + g8];
        c4 = __builtin_amdgcn_mfma_f32_16x16x32_bf16(af, bf, c4, 0, 0, 0);
      }
#pragma unroll
      for (int reg = 0; reg < 4; ++reg) {
        int node = base + rt + (g8 >> 1) + reg;
        if (node < N_N) {
          float o = fmaxf(fmaf(c4[reg], 0.25f, bias_c), 0.f);
          xg[(size_t)node * 64 + ct + l15] = o;
        }
      }
    }
    __syncthreads();
  }
}

// ---- fused GIN (16 waves, 32 nodes/tile): agg + MFMA MLP + LN (+AL/+gate) --
template <int NW, bool FUSE_AL, bool FUSE_GATE>
__global__ __launch_bounds__(64 * NW, 4) void k_gin(const int* __restrict__ indptr, const int* __restrict__ csr,
                                                    const float* __restrict__ xg,
                                                    const float* __restrict__ w1,
                                                    const float* __restrict__ b1, const float* __restrict__ w2,
                                                    const float* __restrict__ b2, const float* __restrict__ lnw,
                                                    const float* __restrict__ lnb,
                                                    float* __restrict__ xo,
                                                    const float* __restrict__ wsv, const float* __restrict__ wdv,
                                                    float* __restrict__ al_s, float* __restrict__ al_d,
                                                    const float* __restrict__ gw1, const float* __restrict__ gb1,
                                                    const float* __restrict__ gw2, const float* __restrict__ gb2,
                                                    float* __restrict__ gate) {
  constexpr int KR = 72;
  __shared__ unsigned short W1t[64][KR], W2t[64][KR];
  __shared__ unsigned short GW1t[FUSE_GATE ? 64 : 1][FUSE_GATE ? KR : 1];
  __shared__ unsigned short WVt[FUSE_AL ? 16 : 1][FUSE_AL ? KR : 1];
  __shared__ unsigned short A1h[32][KR], A1l[32][KR], A2s[32][KR];
  __shared__ float A3[32][68];
  __shared__ unsigned short A4[FUSE_GATE ? 32 : 1][FUSE_GATE ? KR : 1];
  __shared__ float gred[4][32];
  int t = threadIdx.x;
  for (int idx = t; idx < 4096; idx += 64 * NW) {
    int k = idx >> 6, c = idx & 63;
    W1t[c][k] = f2bf(w1[idx]);
    W2t[c][k] = f2bf(w2[idx]);
    if constexpr (FUSE_GATE) GW1t[c][k] = f2bf(gw1[idx]);
  }
  if constexpr (FUSE_AL) {
    for (int idx = t; idx < 16 * 64; idx += 64 * NW) {
      int j = idx >> 6, k = idx & 63;
      float v = (j < 4) ? wsv[j * 64 + k] : (j < 8 ? wdv[(j - 4) * 64 + k] : 0.f);
      WVt[j][k] = f2bf(v);
    }
  }
  __syncthreads();
  int wv = t >> 6, lane = t & 63;
  int l15 = lane & 15, g8 = (lane >> 4) * 8;
  int ct = (wv & 3) * 16, rt = ((wv >> 2) & 1) * 16;  // tile coords (wv<8)
  float b1c = b1[ct + l15], b2c = b2[ct + l15];
  float gb1c = 0.f, gw2c = 0.f;
  if constexpr (FUSE_GATE) {
    gb1c = gb1[ct + l15];
    gw2c = gw2[ct + l15];
  }
  float lnwv = lnw[lane], lnbv = lnb[lane];
  float gb2v = FUSE_GATE ? gb2[0] : 0.f;
  for (int base = blockIdx.x * 32; base < N_N; base += gridDim.x * 32) {
    float xis[2];
#pragma unroll
    for (int rep = 0; rep < 2; ++rep) {
      int i = base + wv * 2 + rep;
      if (i < N_N) {
        int b = indptr[i], e = indptr[i + 1];
        float xi = xg[(size_t)i * 64 + lane];
        xis[rep] = xi;
        float acc = xi;
        for (int j = b; j < e; j += 8) {
          int cj[8];
#pragma unroll
          for (int u = 0; u < 8; ++u) cj[u] = csr[min(j + u, e - 1)];
          float v[8];
#pragma unroll
          for (int u = 0; u < 8; ++u) v[u] = xg[(size_t)cj[u] * 64 + lane];
#pragma unroll
          for (int u = 0; u < 8; ++u) acc += (j + u) < e ? v[u] : 0.f;
        }
        int n = wv * 2 + rep;
        unsigned short hb = f2bf(acc);
        A1h[n][lane] = hb;
        A1l[n][lane] = f2bf(acc - bfs(hb));
      }
    }
    __syncthreads();
    if (wv < 8) {  // MLP1: relu(A1 @ W1 + b1) -> A2 (bf16)
      float4v c4 = {0.f, 0.f, 0.f, 0.f};
#pragma unroll
      for (int kk = 0; kk < 64; kk += 32) {
        short8v bf = *(const short8v*)&W1t[ct + l15][kk + g8];
        short8v ah = *(const short8v*)&A1h[rt + l15][kk + g8];
        c4 = __builtin_amdgcn_mfma_f32_16x16x32_bf16(ah, bf, c4, 0, 0, 0);
        short8v al = *(const short8v*)&A1l[rt + l15][kk + g8];
        c4 = __builtin_amdgcn_mfma_f32_16x16x32_bf16(al, bf, c4, 0, 0, 0);
      }
#pragma unroll
      for (int reg = 0; reg < 4; ++reg)
        A2s[rt + (g8 >> 1) + reg][ct + l15] = f2bf(fmaxf(c4[reg] + b1c, 0.f));
    }
    __syncthreads();
    if (wv < 8) {  // MLP2: A2 @ W2 + b2 -> A3 (f32)
      float4v c4 = {0.f, 0.f, 0.f, 0.f};
#pragma unroll
      for (int kk = 0; kk < 64; kk += 32) {
        short8v af = *(const short8v*)&A2s[rt + l15][kk + g8];
        short8v bf = *(const short8v*)&W2t[ct + l15][kk + g8];
        c4 = __builtin_amdgcn_mfma_f32_16x16x32_bf16(af, bf, c4, 0, 0, 0);
      }
#pragma unroll
      for (int reg = 0; reg < 4; ++reg) A3[rt + (g8 >> 1) + reg][ct + l15] = c4[reg] + b2c;
    }
    __syncthreads();
#pragma unroll
    for (int rep = 0; rep < 2; ++rep) {
      int i = base + wv * 2 + rep;
      if (i < N_N) {
        int n = wv * 2 + rep;
        float res = xis[rep] + A3[n][lane];
        float mu = wsum(res) * (1.f / 64.f);
        float d = res - mu;
        float var = wsum(d * d) * (1.f / 64.f);
        float xov = fmaf(d * rsqrtf(var + LN_EPS), lnwv, lnbv);
        xo[(size_t)i * 64 + lane] = xov;
        if constexpr (FUSE_AL) {
          unsigned short hb = f2bf(xov);
          A1h[n][lane] = hb;
          A1l[n][lane] = f2bf(xov - bfs(hb));
        }
        if constexpr (FUSE_GATE) A4[n][lane] = f2bf(xov);
      }
    }
    if constexpr (FUSE_AL) {
      __syncthreads();
      if (wv < 2) {  // [32 nodes x 64] @ [64 x 16 logit cols]; rows wv*16
        float4v c4 = {0.f, 0.f, 0.f, 0.f};
#pragma unroll
        for (int kk = 0; kk < 64; kk += 32) {
          short8v bf = *(const short8v*)&WVt[l15][kk + g8];
          short8v ah = *(const short8v*)&A1h[wv * 16 + l15][kk + g8];
          c4 = __builtin_amdgcn_mfma_f32_16x16x32_bf16(ah, bf, c4, 0, 0, 0);
          short8v al = *(const short8v*)&A1l[wv * 16 + l15][kk + g8];
          c4 = __builtin_amdgcn_mfma_f32_16x16x32_bf16(al, bf, c4, 0, 0, 0);
        }
#pragma unroll
        for (int reg = 0; reg < 4; ++reg) {
          int node = base + wv * 16 + (g8 >> 1) + reg;
          if (node < N_N) {
            if (l15 < 4) al_s[node * 4 + l15] = c4[reg];
            else if (l15 < 8) al_d[node * 4 + (l15 - 4)] = c4[reg];
          }
        }
      }
      __syncthreads();
    }
    if constexpr (FUSE_GATE) {
      __syncthreads();
      if (wv < 8) {  // gate hidden tile: relu(A4 @ GW1 + gb1) . gw2 (partial)
        float4v c4 = {0.f, 0.f, 0.f, 0.f};
#pragma unroll
        for (int kk = 0; kk < 64; kk += 32) {
          short8v af = *(const short8v*)&A4[rt + l15][kk + g8];
          short8v bf = *(const short8v*)&GW1t[ct + l15][kk + g8];
          c4 = __builtin_amdgcn_mfma_f32_16x16x32_bf16(af, bf, c4, 0, 0, 0);
        }
#pragma unroll
        for (int reg = 0; reg < 4; ++reg) {
          float m = fmaxf(c4[reg] + gb1c, 0.f) * gw2c;
          m += __shfl_xor(m, 1, 64);
          m += __shfl_xor(m, 2, 64);
          m += __shfl_xor(m, 4, 64);
          m += __shfl_xor(m, 8, 64);
          if (l15 == 0) gred[wv & 3][rt + (g8 >> 1) + reg] = m;
        }
      }
      __syncthreads();
      if (wv == 0 && lane < 32) {
        int node = base + lane;
        if (node < N_N)
          gate[node] = gred[0][lane] + gred[1][lane] + gred[2][lane] + gred[3][lane] + gb2v;
      }
      __syncthreads();
    }
  }
}

// ---------------- global attention pool ----------------
__global__ __launch_bounds__(256) void k_pool(const int* __restrict__ gptr, const float* __restrict__ gate,
                                              const float* __restrict__ x2, float* __restrict__ pooled) {
  int g = blockIdx.x;
  int t = threadIdx.x, wv = t >> 6, lane = t & 63;
  __shared__ float red[256];
  int b = gptr[g], e = gptr[g + 1];
  if (b == e) {
    if (t < 64) pooled[g * 64 + t] = 0.f;
    return;
  }
  float m = -1e30f;
  for (int j = b + t; j < e; j += 256) m = fmaxf(m, gate[j]);
  m = wmax(m);
  if (lane == 0) red[wv] = m;
  __syncthreads();
  m = fmaxf(fmaxf(red[0], red[1]), fmaxf(red[2], red[3]));
  __syncthreads();
  float dn = 0.f;
  for (int j = b + t; j < e; j += 256) dn += __expf(gate[j] - m);
  dn = wsum(dn);
  if (lane == 0) red[wv] = dn;
  __syncthreads();
  dn = red[0] + red[1] + red[2] + red[3];
  __syncthreads();
  float acc = 0.f;
  for (int j = b + wv; j < e; j += 4) acc = fmaf(__expf(gate[j] - m), x2[(size_t)j * 64 + lane], acc);
  red[t] = acc;
  __syncthreads();
  if (t < 64) pooled[g * 64 + t] = (red[t] + red[t + 64] + red[t + 128] + red[t + 192]) / dn;
}

// ---------------- head MLP ----------------
__global__ __launch_bounds__(128) void k_head(const float* __restrict__ pooled, const float* __restrict__ l1w,
                                              const float* __restrict__ l1b, const float* __restrict__ lnfw,
                                              const float* __restrict__ lnfb, const float* __restrict__ l2w,
                                              const float* __restrict__ l2b, float* __restrict__ out) {
  int g = blockIdx.x, t = threadIdx.x;
  __shared__ float pl[64], zl[128], red[2];
  if (t < 64) pl[t] = pooled[g * 64 + t];
  __syncthreads();
  float y = l1b[t];
#pragma unroll 8
  for (int k = 0; k < 64; ++k) y = fmaf(pl[k], l1w[k * 128 + t], y);
  int wv = t >> 6, lane = t & 63;
  float s = wsum(y);
  if (lane == 0) red[wv] = s;
  __syncthreads();
  float mu = (red[0] + red[1]) * (1.f / 128.f);
  float d = y - mu;
  __syncthreads();
  s = wsum(d * d);
  if (lane == 0) red[wv] = s;
  __syncthreads();
  float var = (red[0] + red[1]) * (1.f / 128.f);
  float z = fmaxf(fmaf(d * rsqrtf(var + LN_EPS), lnfw[t], lnfb[t]), 0.f);
  zl[t] = z;
  __syncthreads();
  if (t < 6) {
    float o = l2b[t];
    for (int k = 0; k < 128; ++k) o = fmaf(zl[k], l2w[k * 6 + t], o);
    out[g * 6 + t] = o;
  }
}

extern "C" void kernel_launch(void* const* d_in, const int* in_sizes, int n_in,
                              void* d_out, int out_size, void* d_ws, size_t ws_size,
                              hipStream_t stream) {
  const float* x = (const float*)d_in[0];
  const int* src = (const int*)d_in[1];
  const int* dst = (const int*)d_in[2];
  const int* batch = (const int*)d_in[3];
  const float* W1 = (const float*)d_in[4];
  const float* a1s = (const float*)d_in[5];
  const float* a1d = (const float*)d_in[6];
  const float* bg1 = (const float*)d_in[7];
  const float* m1w1 = (const float*)d_in[8];
  const float* m1b1 = (const float*)d_in[9];
  const float* m1w2 = (const float*)d_in[10];
  const float* m1b2 = (const float*)d_in[11];
  const float* ln1w = (const float*)d_in[12];
  const float* ln1b = (const float*)d_in[13];
  const float* W2 = (const float*)d_in[14];
  const float* a2s = (const float*)d_in[15];
  const float* a2d = (const float*)d_in[16];
  const float* bg2 = (const float*)d_in[17];
  const float* m2w1 = (const float*)d_in[18];
  const float* m2b1 = (const float*)d_in[19];
  const float* m2w2 = (const float*)d_in[20];
  const float* m2b2 = (const float*)d_in[21];
  const float* ln2w = (const float*)d_in[22];
  const float* ln2b = (const float*)d_in[23];
  const float* gw1 = (const float*)d_in[24];
  const float* gb1 = (const float*)d_in[25];
  const float* gw2 = (const float*)d_in[26];
  const float* gb2 = (const float*)d_in[27];
  const float* l1w = (const float*)d_in[28];
  const float* l1b = (const float*)d_in[29];
  const float* lnfw = (const float*)d_in[30];
  const float* lnfb = (const float*)d_in[31];
  const float* l2w = (const float*)d_in[32];
  const float* l2b = (const float*)d_in[33];
  float* out = (float*)d_out;

  char* ws = (char*)d_ws;
  size_t off = 0;
  auto alloc = [&](size_t bytes) -> void* {
    void* p = ws + off;
    off += (bytes + 255) & ~(size_t)255;
    return p;
  };
  int* indptr = (int*)alloc((N_N + 1) * sizeof(int));
  int* csr = (int*)alloc((size_t)N_E * sizeof(int));
  unsigned long long* pairs = (unsigned long long*)alloc((size_t)N_E * sizeof(unsigned long long));
  int* ccnt = (int*)alloc(NBKT * sizeof(int));
  int* cbase = (int*)alloc(NBKT * sizeof(int));
  int* cfill = (int*)alloc(NBKT * sizeof(int));
  int* gptr = (int*)alloc(257 * sizeof(int));
  float* wsv = (float*)alloc(HEADS * 64 * sizeof(float));
  float* wdv = (float*)alloc(HEADS * 64 * sizeof(float));
  float* al_s = (float*)alloc((size_t)N_N * 4 * sizeof(float));
  float* al_d = (float*)alloc((size_t)N_N * 4 * sizeof(float));
  float* gate = (float*)alloc((size_t)N_N * sizeof(float));
  float* pooled = (float*)alloc(N_G * 64 * sizeof(float));
  float* xg = (float*)alloc((size_t)N_N * 64 * sizeof(float));
  float* xv = (float*)alloc((size_t)N_N * 64 * sizeof(float));
  (void)ws_size; (void)n_in; (void)in_sizes; (void)out_size;

  const int NCB = (N_E + 4095) / 4096;  // 391

  hipMemsetAsync(ccnt, 0, NBKT * sizeof(int), stream);
  k_ccount<<<NCB, 256, 0, stream>>>(dst, ccnt);
  k_cscan<<<1, 512, 0, stream>>>(ccnt, cbase, cfill);
  k_cscat<<<NCB, 256, 0, stream>>>(src, dst, cfill, pairs);
  k_build<<<NBKT, 256, 0, stream>>>(ccnt, cbase, pairs, indptr, csr);
  k_gbounds<<<1, 512, 0, stream>>>(batch, gptr);

  // ---- layer 1 ----
  k_avec<F_IN><<<1, 256, 0, stream>>>(W1, a1s, a1d, wsv, wdv);
  k_al2<F_IN><<<(N_N + 63) / 64, 256, 0, stream>>>(x, wsv, wdv, al_s, al_d);
  k_gat<F_IN, 16><<<1024, 1024, 0, stream>>>(x, indptr, csr, al_s, al_d, W1, bg1, xg);
  k_avec<CH><<<1, 256, 0, stream>>>(W2, a2s, a2d, wsv, wdv);  // layer-2 logit vectors
  k_gin<16, true, false><<<1024, 1024, 0, stream>>>(indptr, csr, xg, m1w1, m1b1, m1w2, m1b2, ln1w, ln1b,
                                                    xv, wsv, wdv, al_s, al_d, gw1, gb1, gw2, gb2, gate);
  // ---- layer 2 ----
  k_gat<CH, 16><<<1024, 1024, 0, stream>>>(xv, indptr, csr, al_s, al_d, W2, bg2, xg);
  k_gin<16, false, true><<<1024, 1024, 0, stream>>>(indptr, csr, xg, m2w1, m2b1, m2w2, m2b2, ln2w, ln2b,
                                                    xv, wsv, wdv, al_s, al_d, gw1, gb1, gw2, gb2, gate);
  // ---- pooling + head ----
  k_pool<<<N_G, 256, 0, stream>>>(gptr, gate, xv, pooled);
  k_head<<<N_G, 128, 0, stream>>>(pooled, l1w, l1b, lnfw, lnfb, l2w, l2b, out);
}

// Round 16
// 617.464 us; speedup vs baseline: 1.1708x; 1.1015x over previous
//
#include <hip/hip_runtime.h>

#define N_N 100000
#define N_E 1600000
#define N_G 256
#define F_IN 28
#define HEADS 4
#define CH 64
#define NEG 0.2f
#define LN_EPS 1e-5f
#define NBKT 391   // ceil(N_N/256) coarse buckets (256 nodes each)
#define BCAP 6144  // per-bucket pair capacity (mean 4092, sigma 64 -> safe)

typedef __attribute__((ext_vector_type(8))) short short8v;   // 8 bf16
typedef __attribute__((ext_vector_type(4))) float float4v;   // MFMA acc

__device__ __forceinline__ float lrelu(float x) { return x > 0.f ? x : NEG * x; }

__device__ __forceinline__ float wsum(float v) {
#pragma unroll
  for (int o = 32; o > 0; o >>= 1) v += __shfl_xor(v, o, 64);
  return v;
}
__device__ __forceinline__ float wmax(float v) {
#pragma unroll
  for (int o = 32; o > 0; o >>= 1) v = fmaxf(v, __shfl_xor(v, o, 64));
  return v;
}

// bf16 helpers (storage-only compression in LDS)
__device__ __forceinline__ float bfs(unsigned short u) {
  return __uint_as_float((unsigned)u << 16);
}
__device__ __forceinline__ unsigned short f2bf(float v) {
  unsigned u = __float_as_uint(v);
  return (unsigned short)((u + 0x7fff + ((u >> 16) & 1)) >> 16);  // RNE
}

// ---------------- CSR build: two-level bucketed, coalesced ----------------
__global__ __launch_bounds__(256) void k_ccount(const int* __restrict__ dst, int* __restrict__ ccnt) {
  __shared__ int h[NBKT];
  int t = threadIdx.x;
  for (int i = t; i < NBKT; i += 256) h[i] = 0;
  __syncthreads();
  int base = blockIdx.x * 4096;
  int cnt = min(4096, N_E - base);
  for (int j = t; j < cnt; j += 256) atomicAdd(&h[dst[base + j] >> 8], 1);
  __syncthreads();
  for (int i = t; i < NBKT; i += 256)
    if (h[i]) atomicAdd(&ccnt[i], h[i]);
}

__global__ __launch_bounds__(512) void k_cscan(const int* __restrict__ ccnt, int* __restrict__ cbase,
                                               int* __restrict__ cfill) {
  __shared__ int l[512];
  int t = threadIdx.x;
  int v = (t < NBKT) ? ccnt[t] : 0;
  l[t] = v;
  __syncthreads();
  for (int o = 1; o < 512; o <<= 1) {
    int a = (t >= o) ? l[t - o] : 0;
    __syncthreads();
    l[t] += a;
    __syncthreads();
  }
  if (t < NBKT) {
    cbase[t] = l[t] - v;
    cfill[t] = l[t] - v;
  }
}

__global__ __launch_bounds__(256) void k_cscat(const int* __restrict__ src, const int* __restrict__ dst,
                                               int* cfill, unsigned long long* __restrict__ pairs) {
  __shared__ unsigned long long pl[4096];   // 32 KB
  __shared__ unsigned long long outp[4096]; // 32 KB
  __shared__ int h[NBKT], sc[NBKT], gpos[NBKT], f2[NBKT];
  int t = threadIdx.x;
  for (int i = t; i < NBKT; i += 256) {
    h[i] = 0;
    f2[i] = 0;
  }
  __syncthreads();
  int base = blockIdx.x * 4096;
  int cnt = min(4096, N_E - base);
  for (int j = t; j < cnt; j += 256) {
    int d = dst[base + j];
    pl[j] = ((unsigned long long)(unsigned)d << 32) | (unsigned)src[base + j];
    atomicAdd(&h[d >> 8], 1);
  }
  __syncthreads();
  for (int i = t; i < NBKT; i += 256) sc[i] = h[i];
  __syncthreads();
  for (int o = 1; o < NBKT; o <<= 1) {
    int v0 = 0, v1 = 0;
    int i2 = t + 256;
    if (t >= o) v0 = sc[t - o];
    if (i2 < NBKT && i2 >= o) v1 = sc[i2 - o];
    __syncthreads();
    if (t >= o) sc[t] += v0;
    if (i2 < NBKT && i2 >= o) sc[i2] += v1;
    __syncthreads();
  }
  for (int i = t; i < NBKT; i += 256)
    if (h[i]) gpos[i] = atomicAdd(&cfill[i], h[i]);
  __syncthreads();
  for (int j = t; j < cnt; j += 256) {
    unsigned long long p = pl[j];
    int bin = (int)(p >> 40);  // dst>>8
    int r = atomicAdd(&f2[bin], 1);
    outp[sc[bin] - h[bin] + r] = p;
  }
  __syncthreads();
  for (int j = t; j < cnt; j += 256) {
    unsigned long long p = outp[j];
    int bin = (int)(p >> 40);
    pairs[gpos[bin] + (j - (sc[bin] - h[bin]))] = p;
  }
}

__global__ __launch_bounds__(256) void k_build(const int* __restrict__ ccnt, const int* __restrict__ cbase,
                                               const unsigned long long* __restrict__ pairs,
                                               int* __restrict__ indptr, int* __restrict__ csr) {
  __shared__ unsigned long long pl[BCAP];  // 48 KB
  __shared__ int sl[BCAP];                 // 24 KB
  __shared__ int degl[256], lofs[256], fil[256];
  int nb = blockIdx.x, t = threadIdx.x;
  int gbase = cbase[nb], cnt = ccnt[nb];
  int nn = min(256, N_N - nb * 256);
  if (t == 0 && nb == 0) indptr[N_N] = N_E;
  if (cnt <= BCAP) {
    for (int j = t; j < cnt; j += 256) pl[j] = pairs[gbase + j];
    degl[t] = 0;
    __syncthreads();
    for (int j = t; j < cnt; j += 256) atomicAdd(&degl[(int)((pl[j] >> 32) & 255)], 1);
    __syncthreads();
    int v = degl[t];
    lofs[t] = v;
    __syncthreads();
    for (int o = 1; o < 256; o <<= 1) {
      int a = (t >= o) ? lofs[t - o] : 0;
      __syncthreads();
      lofs[t] += a;
      __syncthreads();
    }
    int excl = lofs[t] - v;  // exclusive prefix
    if (t < nn) indptr[nb * 256 + t] = gbase + excl;
    fil[t] = excl;
    __syncthreads();
    for (int j = t; j < cnt; j += 256) {
      unsigned long long p = pl[j];
      int node = (int)((p >> 32) & 255);
      int pos = atomicAdd(&fil[node], 1);
      sl[pos] = (int)(unsigned)p;
    }
    __syncthreads();
    int wv = t >> 6, lane = t & 63;
    for (int q = wv; q < 256; q += 4) {
      int d = degl[q];
      if (d <= 1) continue;
      int b = lofs[q] - d;
      if (d <= 64) {
        int vv = (lane < d) ? sl[b + lane] : 0x7fffffff;
        int rank = 0;
        for (int j2 = 0; j2 < d; ++j2) {
          int vj = __shfl(vv, j2, 64);
          rank += ((vj < vv) || (vj == vv && j2 < lane)) ? 1 : 0;
        }
        if (lane < d) sl[b + rank] = vv;
      } else if (lane == 0) {
        for (int j2 = b + 1; j2 < b + d; ++j2) {
          int key = sl[j2];
          int k2 = j2 - 1;
          while (k2 >= b && sl[k2] > key) { sl[k2 + 1] = sl[k2]; --k2; }
          sl[k2 + 1] = key;
        }
      }
    }
    __syncthreads();
    for (int j = t; j < cnt; j += 256) csr[gbase + j] = sl[j];
  } else if (t == 0) {
    for (int n = 0; n < nn; ++n) degl[n] = 0;
    for (int j = 0; j < cnt; ++j) degl[(int)((pairs[gbase + j] >> 32) & 255)]++;
    int run = 0;
    for (int n = 0; n < nn; ++n) {
      indptr[nb * 256 + n] = gbase + run;
      fil[n] = run;
      run += degl[n];
    }
    for (int j = 0; j < cnt; ++j) {
      unsigned long long p = pairs[gbase + j];
      int node = (int)((p >> 32) & 255);
      csr[gbase + fil[node]++] = (int)(unsigned)p;
    }
    for (int n = 0; n < nn; ++n) {
      int b = indptr[nb * 256 + n], e2 = b + degl[n];
      for (int j2 = b + 1; j2 < e2; ++j2) {
        int key = csr[j2];
        int k2 = j2 - 1;
        while (k2 >= b && csr[k2] > key) { csr[k2 + 1] = csr[k2]; --k2; }
        csr[k2 + 1] = key;
      }
    }
  }
}

// ---------------- graph ranges: batch is SORTED -> binary search ----------
__global__ __launch_bounds__(512) void k_gbounds(const int* __restrict__ batch, int* __restrict__ gptr) {
  int g = threadIdx.x;
  if (g > N_G) return;
  int lo = 0, hi = N_N;
  while (lo < hi) {
    int mid = (lo + hi) >> 1;
    if (batch[mid] < g) lo = mid + 1;
    else hi = mid;
  }
  gptr[g] = lo;
}

// ---------------- attention logits ----------------
template <int F>
__global__ __launch_bounds__(256) void k_avec(const float* __restrict__ W, const float* __restrict__ as_,
                                              const float* __restrict__ ad_, float* __restrict__ wsv,
                                              float* __restrict__ wdv) {
  int idx = blockIdx.x * 256 + threadIdx.x;
  if (idx >= HEADS * F) return;
  int h = idx / F, f = idx % F;
  float s = 0.f, d = 0.f;
  for (int c = 0; c < 64; ++c) {
    float w = W[(h * F + f) * 64 + c];
    s = fmaf(w, as_[h * 64 + c], s);
    d = fmaf(w, ad_[h * 64 + c], d);
  }
  wsv[idx] = s;
  wdv[idx] = d;
}

template <int F>
__global__ __launch_bounds__(256) void k_al2(const float* __restrict__ xin, const float* __restrict__ wsv,
                                             const float* __restrict__ wdv, float* __restrict__ al_s,
                                             float* __restrict__ al_d) {
  constexpr int FP = (F % 2 == 0) ? F + 1 : F;
  __shared__ float xl[64][FP];
  __shared__ float wsl[HEADS][F], wdl[HEADS][F];
  int t = threadIdx.x;
  for (int idx = t; idx < HEADS * F; idx += 256) {
    wsl[idx / F][idx % F] = wsv[idx];
    wdl[idx / F][idx % F] = wdv[idx];
  }
  int base = blockIdx.x * 64;
  for (int idx = t; idx < 64 * F; idx += 256) {
    int n = idx / F, f = idx % F;
    int i = base + n;
    xl[n][f] = (i < N_N) ? xin[(size_t)i * F + f] : 0.f;
  }
  __syncthreads();
  int n = t >> 2, h = t & 3;
  int i = base + n;
  if (i < N_N) {
    float s = 0.f, d = 0.f;
#pragma unroll
    for (int f = 0; f < F; ++f) {
      float xv = xl[n][f];
      s = fmaf(xv, wsl[h][f], s);
      d = fmaf(xv, wdl[h][f], d);
    }
    al_s[i * 4 + h] = s;
    al_d[i * 4 + h] = d;
  }
}

// ---------------- fused GAT layer (8 waves, 16 nodes/tile) ----------------
// 8 waves aggregate 2 nodes each (no max-subtraction: logits provably
// bounded), stage agg to LDS (bf16), 4 waves run the MFMA epilogue.
// 32-bit gather index arithmetic (fits: N_N*F < 2^31).
template <int F, int NW>
__global__ __launch_bounds__(64 * NW, 4) void k_gat(const float* __restrict__ xin, const int* __restrict__ indptr,
                                                    const int* __restrict__ csr, const float* __restrict__ al_s,
                                                    const float* __restrict__ al_d, const float* __restrict__ W,
                                                    const float* __restrict__ bias, float* __restrict__ xg) {
  constexpr int K = HEADS * F;        // 256 / 112
  constexpr int KP = (K + 31) & ~31;  // 256 / 128
  constexpr int KROW = KP + 8;
  __shared__ unsigned short Bt[64][KROW];   // W^T (bf16)
  __shared__ unsigned short Ash[16][KROW];  // agg (bf16)
  __shared__ int s_idx[NW][64];
  __shared__ float4 s_w[NW][64];
  int t = threadIdx.x;
  for (int idx = t; idx < K * 64; idx += 64 * NW) {
    int c = idx & 63, hf = idx >> 6;
    Bt[c][hf] = f2bf(W[(size_t)hf * 64 + c]);
  }
  if constexpr (KP > K) {
    for (int idx = t; idx < 64 * (KP - K); idx += 64 * NW)
      Bt[idx / (KP - K)][K + idx % (KP - K)] = 0;
    for (int idx = t; idx < 16 * (KP - K); idx += 64 * NW)
      Ash[idx / (KP - K)][K + idx % (KP - K)] = 0;
  }
  __syncthreads();
  int wv = t >> 6, lane = t & 63;
  int lanef = lane & 31;
  int half = lane >> 5;
  int l15 = lane & 15, g8 = (lane >> 4) * 8;
  float bias_c = (wv < 4) ? bias[16 * wv + l15] : 0.f;
  for (int base = blockIdx.x * 16; base < N_N; base += gridDim.x * 16) {
#pragma unroll
    for (int rep = 0; rep < 2; ++rep) {
      int i = base + wv * 2 + rep;
      if (i < N_N) {
        int b = indptr[i], e = indptr[i + 1];
        float4 ad4 = *(const float4*)&al_d[i * 4];
        float4 as4 = *(const float4*)&al_s[i * 4];
        float ws0 = __expf(lrelu(as4.x + ad4.x));
        float ws1 = __expf(lrelu(as4.y + ad4.y));
        float ws2 = __expf(lrelu(as4.z + ad4.z));
        float ws3 = __expf(lrelu(as4.w + ad4.w));
        float xself = (lane < F) ? xin[i * F + lane] : 0.f;
        float a0 = ws0 * xself, a1 = ws1 * xself, a2 = ws2 * xself, a3 = ws3 * xself;
        if (F == F_IN && half) { a0 = 0.f; a1 = 0.f; a2 = 0.f; a3 = 0.f; }
        float pd0 = 0.f, pd1 = 0.f, pd2 = 0.f, pd3 = 0.f;
        for (int cb = b; cb < e; cb += 64) {
          int cnt = min(64, e - cb);
          bool act = (cb + lane) < e;
          int s = 0;
          float w0 = 0.f, w1 = 0.f, w2 = 0.f, w3 = 0.f;
          if (act) {
            s = csr[cb + lane];
            float4 a4 = *(const float4*)&al_s[s * 4];
            w0 = __expf(lrelu(a4.x + ad4.x));
            w1 = __expf(lrelu(a4.y + ad4.y));
            w2 = __expf(lrelu(a4.z + ad4.z));
            w3 = __expf(lrelu(a4.w + ad4.w));
          }
          pd0 += w0; pd1 += w1; pd2 += w2; pd3 += w3;
          s_idx[wv][lane] = s;
          s_w[wv][lane] = make_float4(w0, w1, w2, w3);
          if (F == F_IN) {
            for (int je = 0; je < cnt; je += 16) {
              int oj[8];
#pragma unroll
              for (int u = 0; u < 8; ++u) oj[u] = s_idx[wv][je + 2 * u + half] * F_IN + lanef;
              float xr[8];
#pragma unroll
              for (int u = 0; u < 8; ++u) xr[u] = (lanef < F_IN) ? xin[oj[u]] : 0.f;
#pragma unroll
              for (int u = 0; u < 8; ++u) {
                float4 w4 = s_w[wv][je + 2 * u + half];
                a0 = fmaf(w4.x, xr[u], a0);
                a1 = fmaf(w4.y, xr[u], a1);
                a2 = fmaf(w4.z, xr[u], a2);
                a3 = fmaf(w4.w, xr[u], a3);
              }
            }
          } else {
            for (int je = 0; je < cnt; je += 8) {
              int oj[8];
#pragma unroll
              for (int u = 0; u < 8; ++u) oj[u] = s_idx[wv][je + u] * F + lane;
              float xr[8];
#pragma unroll
              for (int u = 0; u < 8; ++u) xr[u] = xin[oj[u]];
#pragma unroll
              for (int u = 0; u < 8; ++u) {
                float4 w4 = s_w[wv][je + u];
                a0 = fmaf(w4.x, xr[u], a0);
                a1 = fmaf(w4.y, xr[u], a1);
                a2 = fmaf(w4.z, xr[u], a2);
                a3 = fmaf(w4.w, xr[u], a3);
              }
            }
          }
        }
        if (F == F_IN) {
          a0 += __shfl_xor(a0, 32, 64);
          a1 += __shfl_xor(a1, 32, 64);
          a2 += __shfl_xor(a2, 32, 64);
          a3 += __shfl_xor(a3, 32, 64);
        }
        float dn0 = wsum(pd0) + ws0;
        float dn1 = wsum(pd1) + ws1;
        float dn2 = wsum(pd2) + ws2;
        float dn3 = wsum(pd3) + ws3;
        a0 /= dn0; a1 /= dn1; a2 /= dn2; a3 /= dn3;
        if (lane < F) {
          int n = wv * 2 + rep;
          Ash[n][0 * F + lane] = f2bf(a0);
          Ash[n][1 * F + lane] = f2bf(a1);
          Ash[n][2 * F + lane] = f2bf(a2);
          Ash[n][3 * F + lane] = f2bf(a3);
        }
      }
    }
    __syncthreads();
    if (wv < 4) {  // MFMA epilogue: wave wv computes C cols [16wv,16wv+16)
      float4v c4 = {0.f, 0.f, 0.f, 0.f};
#pragma unroll
      for (int kk = 0; kk < KP; kk += 32) {
        short8v af = *(const short8v*)&Ash[l15][kk + g8];
        short8v bf = *(const short8v*)&Bt[16 * wv + l15][kk + g8];
        c4 = __builtin_amdgcn_mfma_f32_16x16x32_bf16(af, bf, c4, 0, 0, 0);
      }
#pragma unroll
      for (int reg = 0; reg < 4; ++reg) {
        int node = base + (g8 >> 1) + reg;
        if (node < N_N) {
          float o = fmaxf(fmaf(c4[reg], 0.25f, bias_c), 0.f);
          xg[(size_t)node * 64 + 16 * wv + l15] = o;
        }
      }
    }
    __syncthreads();
  }
}

// ---- fused GIN (8 waves, 16 nodes/tile): agg + MFMA MLP + LN (+AL/+gate) --
template <int NW, bool FUSE_AL, bool FUSE_GATE>
__global__ __launch_bounds__(64 * NW, 4) void k_gin(const int* __restrict__ indptr, const int* __restrict__ csr,
                                                    const float* __restrict__ xg,
                                                    const float* __restrict__ w1,
                                                    const float* __restrict__ b1, const float* __restrict__ w2,
                                                    const float* __restrict__ b2, const float* __restrict__ lnw,
                                                    const float* __restrict__ lnb,
                                                    float* __restrict__ xo,
                                                    const float* __restrict__ wsv, const float* __restrict__ wdv,
                                                    float* __restrict__ al_s, float* __restrict__ al_d,
                                                    const float* __restrict__ gw1, const float* __restrict__ gb1,
                                                    const float* __restrict__ gw2, const float* __restrict__ gb2,
                                                    float* __restrict__ gate) {
  constexpr int KR = 72;
  __shared__ unsigned short W1t[64][KR], W2t[64][KR];
  __shared__ unsigned short GW1t[FUSE_GATE ? 64 : 1][FUSE_GATE ? KR : 1];
  __shared__ unsigned short WVt[FUSE_AL ? 16 : 1][FUSE_AL ? KR : 1];
  __shared__ unsigned short A1h[16][KR], A1l[16][KR], A2s[16][KR];
  __shared__ float A3[16][68];
  __shared__ unsigned short A4[FUSE_GATE ? 16 : 1][FUSE_GATE ? KR : 1];
  __shared__ float gred[4][16];
  int t = threadIdx.x;
  for (int idx = t; idx < 4096; idx += 64 * NW) {
    int k = idx >> 6, c = idx & 63;
    W1t[c][k] = f2bf(w1[idx]);
    W2t[c][k] = f2bf(w2[idx]);
    if constexpr (FUSE_GATE) GW1t[c][k] = f2bf(gw1[idx]);
  }
  if constexpr (FUSE_AL) {
    for (int idx = t; idx < 16 * 64; idx += 64 * NW) {
      int j = idx >> 6, k = idx & 63;
      float v = (j < 4) ? wsv[j * 64 + k] : (j < 8 ? wdv[(j - 4) * 64 + k] : 0.f);
      WVt[j][k] = f2bf(v);
    }
  }
  __syncthreads();
  int wv = t >> 6, lane = t & 63;
  int l15 = lane & 15, g8 = (lane >> 4) * 8;
  float b1c = 0.f, b2c = 0.f, gb1c = 0.f, gw2c = 0.f;
  if (wv < 4) {
    b1c = b1[16 * wv + l15];
    b2c = b2[16 * wv + l15];
    if constexpr (FUSE_GATE) {
      gb1c = gb1[16 * wv + l15];
      gw2c = gw2[16 * wv + l15];
    }
  }
  float lnwv = lnw[lane], lnbv = lnb[lane];
  float gb2v = FUSE_GATE ? gb2[0] : 0.f;
  for (int base = blockIdx.x * 16; base < N_N; base += gridDim.x * 16) {
    float xis[2];
#pragma unroll
    for (int rep = 0; rep < 2; ++rep) {
      int i = base + wv * 2 + rep;
      if (i < N_N) {
        int b = indptr[i], e = indptr[i + 1];
        float xi = xg[i * 64 + lane];
        xis[rep] = xi;
        float acc = xi;
        for (int j = b; j < e; j += 8) {
          int oj[8];
#pragma unroll
          for (int u = 0; u < 8; ++u) oj[u] = csr[min(j + u, e - 1)] * 64 + lane;
          float v[8];
#pragma unroll
          for (int u = 0; u < 8; ++u) v[u] = xg[oj[u]];
#pragma unroll
          for (int u = 0; u < 8; ++u) acc += (j + u) < e ? v[u] : 0.f;
        }
        int n = wv * 2 + rep;
        unsigned short hb = f2bf(acc);
        A1h[n][lane] = hb;
        A1l[n][lane] = f2bf(acc - bfs(hb));
      }
    }
    __syncthreads();
    if (wv < 4) {  // MLP1: relu(A1 @ W1 + b1) -> A2 (bf16)
      float4v c4 = {0.f, 0.f, 0.f, 0.f};
#pragma unroll
      for (int kk = 0; kk < 64; kk += 32) {
        short8v bf = *(const short8v*)&W1t[16 * wv + l15][kk + g8];
        short8v ah = *(const short8v*)&A1h[l15][kk + g8];
        c4 = __builtin_amdgcn_mfma_f32_16x16x32_bf16(ah, bf, c4, 0, 0, 0);
        short8v al = *(const short8v*)&A1l[l15][kk + g8];
        c4 = __builtin_amdgcn_mfma_f32_16x16x32_bf16(al, bf, c4, 0, 0, 0);
      }
#pragma unroll
      for (int reg = 0; reg < 4; ++reg)
        A2s[(g8 >> 1) + reg][16 * wv + l15] = f2bf(fmaxf(c4[reg] + b1c, 0.f));
    }
    __syncthreads();
    if (wv < 4) {  // MLP2: A2 @ W2 + b2 -> A3 (f32)
      float4v c4 = {0.f, 0.f, 0.f, 0.f};
#pragma unroll
      for (int kk = 0; kk < 64; kk += 32) {
        short8v af = *(const short8v*)&A2s[l15][kk + g8];
        short8v bf = *(const short8v*)&W2t[16 * wv + l15][kk + g8];
        c4 = __builtin_amdgcn_mfma_f32_16x16x32_bf16(af, bf, c4, 0, 0, 0);
      }
#pragma unroll
      for (int reg = 0; reg < 4; ++reg) A3[(g8 >> 1) + reg][16 * wv + l15] = c4[reg] + b2c;
    }
    __syncthreads();
#pragma unroll
    for (int rep = 0; rep < 2; ++rep) {
      int i = base + wv * 2 + rep;
      if (i < N_N) {
        int n = wv * 2 + rep;
        float res = xis[rep] + A3[n][lane];
        float mu = wsum(res) * (1.f / 64.f);
        float d = res - mu;
        float var = wsum(d * d) * (1.f / 64.f);
        float xov = fmaf(d * rsqrtf(var + LN_EPS), lnwv, lnbv);
        xo[(size_t)i * 64 + lane] = xov;
        if constexpr (FUSE_AL) {
          unsigned short hb = f2bf(xov);
          A1h[n][lane] = hb;
          A1l[n][lane] = f2bf(xov - bfs(hb));
        }
        if constexpr (FUSE_GATE) A4[n][lane] = f2bf(xov);
      }
    }
    if constexpr (FUSE_AL) {
      __syncthreads();
      if (wv == 0) {  // [16 nodes x 64] @ [64 x 16 logit cols] (8 used)
        float4v c4 = {0.f, 0.f, 0.f, 0.f};
#pragma unroll
        for (int kk = 0; kk < 64; kk += 32) {
          short8v bf = *(const short8v*)&WVt[l15][kk + g8];
          short8v ah = *(const short8v*)&A1h[l15][kk + g8];
          c4 = __builtin_amdgcn_mfma_f32_16x16x32_bf16(ah, bf, c4, 0, 0, 0);
          short8v al = *(const short8v*)&A1l[l15][kk + g8];
          c4 = __builtin_amdgcn_mfma_f32_16x16x32_bf16(al, bf, c4, 0, 0, 0);
        }
#pragma unroll
        for (int reg = 0; reg < 4; ++reg) {
          int node = base + (g8 >> 1) + reg;
          if (node < N_N) {
            if (l15 < 4) al_s[node * 4 + l15] = c4[reg];
            else if (l15 < 8) al_d[node * 4 + (l15 - 4)] = c4[reg];
          }
        }
      }
      __syncthreads();
    }
    if constexpr (FUSE_GATE) {
      __syncthreads();
      if (wv < 4) {  // gate hidden: relu(A4 @ GW1 + gb1), then dot with gw2
        float4v c4 = {0.f, 0.f, 0.f, 0.f};
#pragma unroll
        for (int kk = 0; kk < 64; kk += 32) {
          short8v af = *(const short8v*)&A4[l15][kk + g8];
          short8v bf = *(const short8v*)&GW1t[16 * wv + l15][kk + g8];
          c4 = __builtin_amdgcn_mfma_f32_16x16x32_bf16(af, bf, c4, 0, 0, 0);
        }
#pragma unroll
        for (int reg = 0; reg < 4; ++reg) {
          float m = fmaxf(c4[reg] + gb1c, 0.f) * gw2c;
          m += __shfl_xor(m, 1, 64);
          m += __shfl_xor(m, 2, 64);
          m += __shfl_xor(m, 4, 64);
          m += __shfl_xor(m, 8, 64);
          if (l15 == 0) gred[wv][(g8 >> 1) + reg] = m;
        }
      }
      __syncthreads();
      if (wv == 0 && lane < 16) {
        int node = base + lane;
        if (node < N_N)
          gate[node] = gred[0][lane] + gred[1][lane] + gred[2][lane] + gred[3][lane] + gb2v;
      }
      __syncthreads();
    }
  }
}

// ---------------- global attention pool ----------------
__global__ __launch_bounds__(256) void k_pool(const int* __restrict__ gptr, const float* __restrict__ gate,
                                              const float* __restrict__ x2, float* __restrict__ pooled) {
  int g = blockIdx.x;
  int t = threadIdx.x, wv = t >> 6, lane = t & 63;
  __shared__ float red[256];
  int b = gptr[g], e = gptr[g + 1];
  if (b == e) {
    if (t < 64) pooled[g * 64 + t] = 0.f;
    return;
  }
  float m = -1e30f;
  for (int j = b + t; j < e; j += 256) m = fmaxf(m, gate[j]);
  m = wmax(m);
  if (lane == 0) red[wv] = m;
  __syncthreads();
  m = fmaxf(fmaxf(red[0], red[1]), fmaxf(red[2], red[3]));
  __syncthreads();
  float dn = 0.f;
  for (int j = b + t; j < e; j += 256) dn += __expf(gate[j] - m);
  dn = wsum(dn);
  if (lane == 0) red[wv] = dn;
  __syncthreads();
  dn = red[0] + red[1] + red[2] + red[3];
  __syncthreads();
  float acc = 0.f;
  for (int j = b + wv; j < e; j += 4) acc = fmaf(__expf(gate[j] - m), x2[(size_t)j * 64 + lane], acc);
  red[t] = acc;
  __syncthreads();
  if (t < 64) pooled[g * 64 + t] = (red[t] + red[t + 64] + red[t + 128] + red[t + 192]) / dn;
}

// ---------------- head MLP ----------------
__global__ __launch_bounds__(128) void k_head(const float* __restrict__ pooled, const float* __restrict__ l1w,
                                              const float* __restrict__ l1b, const float* __restrict__ lnfw,
                                              const float* __restrict__ lnfb, const float* __restrict__ l2w,
                                              const float* __restrict__ l2b, float* __restrict__ out) {
  int g = blockIdx.x, t = threadIdx.x;
  __shared__ float pl[64], zl[128], red[2];
  if (t < 64) pl[t] = pooled[g * 64 + t];
  __syncthreads();
  float y = l1b[t];
#pragma unroll 8
  for (int k = 0; k < 64; ++k) y = fmaf(pl[k], l1w[k * 128 + t], y);
  int wv = t >> 6, lane = t & 63;
  float s = wsum(y);
  if (lane == 0) red[wv] = s;
  __syncthreads();
  float mu = (red[0] + red[1]) * (1.f / 128.f);
  float d = y - mu;
  __syncthreads();
  s = wsum(d * d);
  if (lane == 0) red[wv] = s;
  __syncthreads();
  float var = (red[0] + red[1]) * (1.f / 128.f);
  float z = fmaxf(fmaf(d * rsqrtf(var + LN_EPS), lnfw[t], lnfb[t]), 0.f);
  zl[t] = z;
  __syncthreads();
  if (t < 6) {
    float o = l2b[t];
    for (int k = 0; k < 128; ++k) o = fmaf(zl[k], l2w[k * 6 + t], o);
    out[g * 6 + t] = o;
  }
}

extern "C" void kernel_launch(void* const* d_in, const int* in_sizes, int n_in,
                              void* d_out, int out_size, void* d_ws, size_t ws_size,
                              hipStream_t stream) {
  const float* x = (const float*)d_in[0];
  const int* src = (const int*)d_in[1];
  const int* dst = (const int*)d_in[2];
  const int* batch = (const int*)d_in[3];
  const float* W1 = (const float*)d_in[4];
  const float* a1s = (const float*)d_in[5];
  const float* a1d = (const float*)d_in[6];
  const float* bg1 = (const float*)d_in[7];
  const float* m1w1 = (const float*)d_in[8];
  const float* m1b1 = (const float*)d_in[9];
  const float* m1w2 = (const float*)d_in[10];
  const float* m1b2 = (const float*)d_in[11];
  const float* ln1w = (const float*)d_in[12];
  const float* ln1b = (const float*)d_in[13];
  const float* W2 = (const float*)d_in[14];
  const float* a2s = (const float*)d_in[15];
  const float* a2d = (const float*)d_in[16];
  const float* bg2 = (const float*)d_in[17];
  const float* m2w1 = (const float*)d_in[18];
  const float* m2b1 = (const float*)d_in[19];
  const float* m2w2 = (const float*)d_in[20];
  const float* m2b2 = (const float*)d_in[21];
  const float* ln2w = (const float*)d_in[22];
  const float* ln2b = (const float*)d_in[23];
  const float* gw1 = (const float*)d_in[24];
  const float* gb1 = (const float*)d_in[25];
  const float* gw2 = (const float*)d_in[26];
  const float* gb2 = (const float*)d_in[27];
  const float* l1w = (const float*)d_in[28];
  const float* l1b = (const float*)d_in[29];
  const float* lnfw = (const float*)d_in[30];
  const float* lnfb = (const float*)d_in[31];
  const float* l2w = (const float*)d_in[32];
  const float* l2b = (const float*)d_in[33];
  float* out = (float*)d_out;

  char* ws = (char*)d_ws;
  size_t off = 0;
  auto alloc = [&](size_t bytes) -> void* {
    void* p = ws + off;
    off += (bytes + 255) & ~(size_t)255;
    return p;
  };
  int* indptr = (int*)alloc((N_N + 1) * sizeof(int));
  int* csr = (int*)alloc((size_t)N_E * sizeof(int));
  unsigned long long* pairs = (unsigned long long*)alloc((size_t)N_E * sizeof(unsigned long long));
  int* ccnt = (int*)alloc(NBKT * sizeof(int));
  int* cbase = (int*)alloc(NBKT * sizeof(int));
  int* cfill = (int*)alloc(NBKT * sizeof(int));
  int* gptr = (int*)alloc(257 * sizeof(int));
  float* wsv = (float*)alloc(HEADS * 64 * sizeof(float));
  float* wdv = (float*)alloc(HEADS * 64 * sizeof(float));
  float* al_s = (float*)alloc((size_t)N_N * 4 * sizeof(float));
  float* al_d = (float*)alloc((size_t)N_N * 4 * sizeof(float));
  float* gate = (float*)alloc((size_t)N_N * sizeof(float));
  float* pooled = (float*)alloc(N_G * 64 * sizeof(float));
  float* xg = (float*)alloc((size_t)N_N * 64 * sizeof(float));
  float* xv = (float*)alloc((size_t)N_N * 64 * sizeof(float));
  (void)ws_size; (void)n_in; (void)in_sizes; (void)out_size;

  const int NCB = (N_E + 4095) / 4096;  // 391

  hipMemsetAsync(ccnt, 0, NBKT * sizeof(int), stream);
  k_ccount<<<NCB, 256, 0, stream>>>(dst, ccnt);
  k_cscan<<<1, 512, 0, stream>>>(ccnt, cbase, cfill);
  k_cscat<<<NCB, 256, 0, stream>>>(src, dst, cfill, pairs);
  k_build<<<NBKT, 256, 0, stream>>>(ccnt, cbase, pairs, indptr, csr);
  k_gbounds<<<1, 512, 0, stream>>>(batch, gptr);

  // ---- layer 1 ----
  k_avec<F_IN><<<1, 256, 0, stream>>>(W1, a1s, a1d, wsv, wdv);
  k_al2<F_IN><<<(N_N + 63) / 64, 256, 0, stream>>>(x, wsv, wdv, al_s, al_d);
  k_gat<F_IN, 8><<<2048, 512, 0, stream>>>(x, indptr, csr, al_s, al_d, W1, bg1, xg);
  k_avec<CH><<<1, 256, 0, stream>>>(W2, a2s, a2d, wsv, wdv);  // layer-2 logit vectors
  k_gin<8, true, false><<<2048, 512, 0, stream>>>(indptr, csr, xg, m1w1, m1b1, m1w2, m1b2, ln1w, ln1b,
                                                  xv, wsv, wdv, al_s, al_d, gw1, gb1, gw2, gb2, gate);
  // ---- layer 2 ----
  k_gat<CH, 8><<<2048, 512, 0, stream>>>(xv, indptr, csr, al_s, al_d, W2, bg2, xg);
  k_gin<8, false, true><<<2048, 512, 0, stream>>>(indptr, csr, xg, m2w1, m2b1, m2w2, m2b2, ln2w, ln2b,
                                                  xv, wsv, wdv, al_s, al_d, gw1, gb1, gw2, gb2, gate);
  // ---- pooling + head ----
  k_pool<<<N_G, 256, 0, stream>>>(gptr, gate, xv, pooled);
  k_head<<<N_G, 128, 0, stream>>>(pooled, l1w, l1b, lnfw, lnfb, l2w, l2b, out);
}